// Round 9
// baseline (1753.983 us; speedup 1.0000x reference)
//
#include <hip/hip_runtime.h>
#include <hip/hip_bf16.h>

typedef unsigned int uint;
typedef unsigned short ushort;

#define NN 65536
#define NE 1048576
#define DD 128
#define TOTE (NE + NN)   // 1114112

__device__ __forceinline__ float b2f(ushort u) {
    uint v = ((uint)u) << 16; float f; __builtin_memcpy(&f, &v, 4); return f;
}
__device__ __forceinline__ ushort f2b(float f) {
    uint x; __builtin_memcpy(&x, &f, 4);
    uint r = (x + 0x7fffu + ((x >> 16) & 1u)) >> 16;
    return (ushort)r;
}

typedef __bf16 bf16x8 __attribute__((ext_vector_type(8)));
typedef float f32x4 __attribute__((ext_vector_type(4)));
typedef float f32x2 __attribute__((ext_vector_type(2)));

// unpack 2 bf16 (packed in uint) -> packed float2, no cvt needed
__device__ __forceinline__ f32x2 bf2f2(uint u) {
    union { uint i; float f; } lo, hi;
    lo.i = u << 16; hi.i = u & 0xffff0000u;
    return (f32x2){lo.f, hi.f};
}

// Canary protocol (kept permanently; perf-free): each pre-final kernel writes a
// distinct constant into a distinct slot of out[0..9]; the FINAL k_attn
// overwrites them with real values. On a mid-pipeline failure, absmax decodes
// the last kernel that ran (100,120,...,280; bands disjoint vs max|ref|=6.5).

// ---------- init: transpose W (fp32 k-major -> bf16 n-major) + zero cnt/sumbuf ----------
__global__ void k_init(const float* __restrict__ Wl, const float* __restrict__ Wr,
                       ushort* __restrict__ WT, int* __restrict__ cnt, float* __restrict__ sumbuf,
                       float* __restrict__ cano) {
    if (cano && blockIdx.x == 0 && blockIdx.y == 0 && blockIdx.z == 0 && threadIdx.x == 0)
        cano[0] = 100.0f;
    // grid (128, 2, 3), block 128
    int k = blockIdx.x, n = threadIdx.x, lr = blockIdx.y, layer = blockIdx.z;
    const float* W = (lr ? Wr : Wl) + layer * 16384;
    WT[(layer * 2 + lr) * 16384 + n * 128 + k] = f2b(W[k * 128 + n]);
    int gid = ((blockIdx.z * 2 + blockIdx.y) * 128 + blockIdx.x) * 128 + threadIdx.x;
    if (gid < NN) cnt[gid] = 0;
    if (gid == NN) sumbuf[0] = 0.f;
}

// ---------- histogram by dst (+self loops) fused with edge_attr sum ----------
__global__ void k_histsum(const int* __restrict__ dst, const float* __restrict__ ea,
                          int* __restrict__ cnt, float* __restrict__ sum,
                          float* __restrict__ cano) {
    if (cano && blockIdx.x == 0 && threadIdx.x == 0) cano[1] = 120.0f;
    __shared__ float red[256];
    int t = threadIdx.x;
    int e = blockIdx.x * 256 + t;     // grid covers TOTE exactly
    int d = (e < NE) ? dst[e] : (e - NE);
    atomicAdd(&cnt[d], 1);
    float s = (e < NE) ? ea[e] : 0.f;
    red[t] = s; __syncthreads();
    for (int o = 128; o > 0; o >>= 1) { if (t < o) red[t] += red[t + o]; __syncthreads(); }
    if (t == 0 && red[0] != 0.f) atomicAdd(sum, red[0]);
}

__global__ void k_scanA(const int* __restrict__ cnt, int* __restrict__ row_off, int* __restrict__ bsum,
                        float* __restrict__ cano) {
    if (cano && blockIdx.x == 0 && threadIdx.x == 0) cano[2] = 140.0f;
    __shared__ int tmp[256];
    int t = threadIdx.x, i = blockIdx.x * 256 + t;
    int v = cnt[i]; tmp[t] = v; __syncthreads();
    for (int off = 1; off < 256; off <<= 1) {
        int x = (t >= off) ? tmp[t - off] : 0;
        __syncthreads();
        tmp[t] += x;
        __syncthreads();
    }
    row_off[i] = tmp[t] - v;
    if (t == 255) bsum[blockIdx.x] = tmp[255];
}

// scanC with local re-scan of bsum (eliminates scanB dispatch)
__global__ void k_scanC(int* __restrict__ row_off, const int* __restrict__ bsum, int* __restrict__ cursor,
                        float* __restrict__ cano) {
    if (cano && blockIdx.x == 0 && threadIdx.x == 0) cano[3] = 160.0f;
    __shared__ int tmp[256];
    __shared__ int excl[256];
    int t = threadIdx.x;
    int v = bsum[t]; tmp[t] = v; __syncthreads();
    for (int off = 1; off < 256; off <<= 1) {
        int x = (t >= off) ? tmp[t - off] : 0;
        __syncthreads();
        tmp[t] += x;
        __syncthreads();
    }
    excl[t] = tmp[t] - v;
    __syncthreads();
    int offb = excl[blockIdx.x];
    int i = blockIdx.x * 256 + t;
    int nv = row_off[i] + offb;
    row_off[i] = nv;
    cursor[i] = nv;
    if (i == 0) row_off[NN] = TOTE;
}

// adj.x stores src<<8 (byte offset into bf16 row array: src*128ch*2B)
__global__ void k_scatter(const int* __restrict__ src, const int* __restrict__ dst,
                          const float* __restrict__ ea, const float* __restrict__ sum,
                          int* __restrict__ cursor, int2* __restrict__ adj,
                          float* __restrict__ cano) {
    if (cano && blockIdx.x == 0 && threadIdx.x == 0) cano[4] = 180.0f;
    int e = blockIdx.x * 256 + threadIdx.x;
    int s, d; float a;
    if (e < NE) { s = src[e]; d = dst[e]; a = ea[e]; }
    else        { s = e - NE; d = s;      a = sum[0] * (1.0f / NE); }
    int pos = atomicAdd(&cursor[d], 1);
    adj[pos] = make_int2(s << 8, __float_as_int(a));
}

// ---------- dual GEMM: xl = src@Wl + bl, xr = src@Wr + br  (bf16 MFMA 16x16x32) ----------
#define LDA 136   // bf16 elems per A row in LDS (272B stride, 16B aligned)

template<bool F32SRC>
__global__ __launch_bounds__(256) void k_gemm(const void* __restrict__ srcv, const ushort* __restrict__ WT,
                                              const float* __restrict__ bl, const float* __restrict__ br,
                                              ushort* __restrict__ xl, ushort* __restrict__ xr,
                                              float* __restrict__ cano, int cslot, float cval) {
    if (cano && blockIdx.x == 0 && threadIdx.x == 0) cano[cslot] = cval;
    __shared__ ushort A[64 * LDA];
    int t = threadIdx.x;
    int rowbase = blockIdx.x * 64;

    if (F32SRC) {
        const float* src = (const float*)srcv;
        #pragma unroll
        for (int it = 0; it < 8; it++) {
            int idx = it * 256 + t;          // 2048 chunks of 4 floats
            int r = idx >> 5, cc = (idx & 31) * 4;
            float4 v = *(const float4*)&src[(size_t)(rowbase + r) * 128 + cc];
            ushort4 pk; pk.x = f2b(v.x); pk.y = f2b(v.y); pk.z = f2b(v.z); pk.w = f2b(v.w);
            *(ushort4*)&A[r * LDA + cc] = pk;
        }
    } else {
        const ushort* src = (const ushort*)srcv;
        #pragma unroll
        for (int it = 0; it < 4; it++) {
            int idx = it * 256 + t;          // 1024 chunks of 8 bf16
            int r = idx >> 4, cc = (idx & 15) * 8;
            *(bf16x8*)&A[r * LDA + cc] = *(const bf16x8*)&src[(size_t)(rowbase + r) * 128 + cc];
        }
    }
    __syncthreads();

    int wave = t >> 6, lane = t & 63;
    int row16 = lane & 15, quad = lane >> 4;

    f32x4 accl[8], accr[8];
    for (int i = 0; i < 8; i++) {
        accl[i] = (f32x4){0.f, 0.f, 0.f, 0.f};
        accr[i] = (f32x4){0.f, 0.f, 0.f, 0.f};
    }

    for (int ks = 0; ks < 4; ks++) {
        bf16x8 a = *(const bf16x8*)&A[(wave * 16 + row16) * LDA + ks * 32 + quad * 8];
        for (int tc = 0; tc < 8; tc++) {
            int coln = tc * 16 + row16;                 // B fragment: n = lane&15
            bf16x8 b_l = *(const bf16x8*)&WT[coln * 128 + ks * 32 + quad * 8];
            bf16x8 b_r = *(const bf16x8*)&WT[16384 + coln * 128 + ks * 32 + quad * 8];
            accl[tc] = __builtin_amdgcn_mfma_f32_16x16x32_bf16(a, b_l, accl[tc], 0, 0, 0);
            accr[tc] = __builtin_amdgcn_mfma_f32_16x16x32_bf16(a, b_r, accr[tc], 0, 0, 0);
        }
    }

    for (int tc = 0; tc < 8; tc++) {
        int col = tc * 16 + row16;                      // C/D: col = lane&15
        float bbl = bl[col], bbr = br[col];
        for (int r = 0; r < 4; r++) {
            int row = rowbase + wave * 16 + quad * 4 + r;   // C/D: row = quad*4 + reg
            size_t o = (size_t)row * 128 + col;
            xl[o] = f2b(accl[tc][r] + bbl);
            xr[o] = f2b(accr[tc][r] + bbr);
        }
    }
}

// ---------- fused attention: PERSISTENT waves + 4-group register prologue ----------
// Grid = NN/16 = 4096 blocks x 128 thr = exactly 16 blocks/CU (LDS 10240B x 16 =
// 160KiB, VGPR<=64 -> 8 waves/SIMD): all waves resident from t=0, no dispatch
// churn (round-8 diagnosis: 32768 short blocks averaged only ~13/32 waves/CU).
// Each wave owns 8 CONTIGUOUS nodes (row_off chained across them; xr/hin reads
// L2-local); we2/at2 register caches hoisted to once per wave (was once per node).
// Per node: 4-group prologue (verified round 8, +8%): adj + xl-row loads for
// degree<=32 issued back-to-back -> one latency exposure; degree>32 tail serial.
// Lane = (p=lane>>3: edge slot, cl=lane&7: 16-ch block). accbuf stride 20 spreads
// banks. Two barriers per node (fill->read, read->next-fill), uniform across both
// waves (both loop exactly 8x). __launch_bounds__(128,8) pins the 64-VGPR tier
// the compiler already chose (prevents +1-reg occupancy cliff).
template<int H, bool FINAL>
__global__ __launch_bounds__(128, 8) void k_attn(
    const ushort* __restrict__ xl, const ushort* __restrict__ xr,
    const int* __restrict__ row_off, const int2* __restrict__ adj,
    const float* __restrict__ We, const float* __restrict__ att,
    const float* __restrict__ bias, const float* __restrict__ ln_g, const float* __restrict__ ln_b,
    const float* __restrict__ hin, float* __restrict__ hout, ushort* __restrict__ hb,
    float* __restrict__ outp,
    float* __restrict__ cano, int cslot, float cval)
{
    if (cano && blockIdx.x == 0 && threadIdx.x == 0) cano[cslot] = cval;
    __shared__ float accbuf[2][8][160];   // [wave][p][cl*20 + 0..15] — bank-spread layout

    int wv = threadIdx.x >> 6, lane = threadIdx.x & 63;
    int gw = blockIdx.x * 2 + wv;        // global wave id, 0..8191
    int p = lane >> 3;          // edge slot within 8-edge group
    int cl = lane & 7;          // channel block: ch [16*cl, 16*cl+16)
    int c16 = cl * 16;
    const char* xlb = (const char*)xl;

    // register caches (packed pairs) — hoisted once per wave (8 nodes)
    f32x2 we2[8], at2[8];
    #pragma unroll
    for (int k = 0; k < 8; k++) {
        we2[k] = (f32x2){We[c16 + 2 * k], We[c16 + 2 * k + 1]};
        at2[k] = (f32x2){att[c16 + 2 * k], att[c16 + 2 * k + 1]};
    }
    int c0 = 2 * lane;
    int rb = (c0 >> 4) * 20 + (c0 & 15);

    int nbase = gw * 8;
    int sA = row_off[nbase];

    for (int nn = 0; nn < 8; ++nn) {
        int n = nbase + nn;
        int s1 = row_off[n + 1];
        int s0 = sA; sA = s1;            // chain: this node's end = next node's start

        // xr row for this node (packed pairs)
        f32x2 xrl2[8];
        {
            uint4 r0 = *(const uint4*)&xr[(size_t)n * 128 + c16];
            uint4 r1 = *(const uint4*)&xr[(size_t)n * 128 + c16 + 8];
            xrl2[0] = bf2f2(r0.x); xrl2[1] = bf2f2(r0.y); xrl2[2] = bf2f2(r0.z); xrl2[3] = bf2f2(r0.w);
            xrl2[4] = bf2f2(r1.x); xrl2[5] = bf2f2(r1.y); xrl2[6] = bf2f2(r1.z); xrl2[7] = bf2f2(r1.w);
        }

        int iters = (s1 - s0 + 7) >> 3;     // >= 1 (self-loop)

        float l_run = 0.f;
        f32x2 acc[8];
        #pragma unroll
        for (int k = 0; k < 8; k++) acc[k] = (f32x2){0.f, 0.f};

        // ---- 4-group register prologue: issue all adj loads, then all gathers ----
        int j0 = s0 + p,      j1 = s0 + 8 + p,  j2 = s0 + 16 + p, j3 = s0 + 24 + p;
        int i0 = (j0 < s1) ? j0 : s0;
        int i1 = (j1 < s1) ? j1 : s0;
        int i2 = (j2 < s1) ? j2 : s0;
        int i3 = (j3 < s1) ? j3 : s0;
        int2 a0 = adj[i0], a1 = adj[i1], a2 = adj[i2], a3 = adj[i3];
        float ea0 = (j0 < s1) ? __int_as_float(a0.y) : 0.f;
        float ea1 = (j1 < s1) ? __int_as_float(a1.y) : 0.f;
        float ea2v = (j2 < s1) ? __int_as_float(a2.y) : 0.f;
        float ea3 = (j3 < s1) ? __int_as_float(a3.y) : 0.f;
        const char* q0 = xlb + (size_t)(uint)a0.x + (cl << 5);
        const char* q1 = xlb + (size_t)(uint)a1.x + (cl << 5);
        const char* q2 = xlb + (size_t)(uint)a2.x + (cl << 5);
        const char* q3 = xlb + (size_t)(uint)a3.x + (cl << 5);
        uint4 u00 = *(const uint4*)q0, u01 = *(const uint4*)(q0 + 16);
        uint4 u10 = *(const uint4*)q1, u11 = *(const uint4*)(q1 + 16);
        uint4 u20 = *(const uint4*)q2, u21 = *(const uint4*)(q2 + 16);
        uint4 u30 = *(const uint4*)q3, u31 = *(const uint4*)(q3 + 16);

        // consume one 8-edge group held in registers (identical math to baseline)
        auto consume = [&](uint4 u0, uint4 u1, float ea_c, int itx) {
            bool valid = (s0 + itx * 8 + p) < s1;
            f32x2 xf[8];
            xf[0] = bf2f2(u0.x); xf[1] = bf2f2(u0.y); xf[2] = bf2f2(u0.z); xf[3] = bf2f2(u0.w);
            xf[4] = bf2f2(u1.x); xf[5] = bf2f2(u1.y); xf[6] = bf2f2(u1.z); xf[7] = bf2f2(u1.w);

            f32x2 ea2 = (f32x2){ea_c, ea_c};
            f32x2 s2 = (f32x2){0.f, 0.f};
            #pragma unroll
            for (int k = 0; k < 8; k++) {
                f32x2 m = xf[k] + __builtin_elementwise_fma(ea2, we2[k], xrl2[k]);
                m = __builtin_elementwise_max(m, 0.2f * m);     // leaky_relu(0.2)
                s2 = __builtin_elementwise_fma(m, at2[k], s2);
            }
            float s = s2.x + s2.y;
            // head reduction across cl lanes of same edge
            s += __shfl_xor(s, 1);
            if (H == 1) { s += __shfl_xor(s, 2); s += __shfl_xor(s, 4); }
            if (!valid) s = -1e30f;

            float e = __expf(s);                 // 0 for invalid; no overflow (|s| small)
            l_run += e;
            f32x2 e2 = (f32x2){e, e};
            #pragma unroll
            for (int k = 0; k < 8; k++) acc[k] = __builtin_elementwise_fma(e2, xf[k], acc[k]);
        };

        consume(u00, u01, ea0, 0);
        if (iters > 1) consume(u10, u11, ea1, 1);
        if (iters > 2) consume(u20, u21, ea2v, 2);
        if (iters > 3) consume(u30, u31, ea3, 3);
        // rare tail: degree > 32 (~0.03% of nodes), simple serial loads
        for (int it = 4; it < iters; ++it) {
            int jn = s0 + it * 8 + p;
            int jb = (jn < s1) ? jn : s0;
            int2 pk = adj[jb];
            float ean = (jn < s1) ? __int_as_float(pk.y) : 0.f;
            const char* rp = xlb + (size_t)(uint)pk.x + (cl << 5);
            uint4 nu0 = *(const uint4*)rp;
            uint4 nu1 = *(const uint4*)(rp + 16);
            consume(nu0, nu1, ean, it);
        }

        // per-head denominator over the 8 edge slots (p)
        l_run += __shfl_xor(l_run, 8);
        l_run += __shfl_xor(l_run, 16);
        l_run += __shfl_xor(l_run, 32);
        float inv = 1.0f / (l_run + 1e-16f);     // matches this lane's channels' head

        // write inv-premultiplied partials to LDS tile (bank-spread: base cl*20)
        float* row = &accbuf[wv][p][cl * 20];
        #pragma unroll
        for (int i = 0; i < 4; i++)
            *(float4*)&row[4 * i] = make_float4(acc[2 * i].x * inv, acc[2 * i].y * inv,
                                                acc[2 * i + 1].x * inv, acc[2 * i + 1].y * inv);
        __syncthreads();

        // each lane sums its 2 channels across the 8 p-slots
        float o0 = 0.f, o1 = 0.f;
        #pragma unroll
        for (int q = 0; q < 8; q++) {
            float2 v = *(float2*)&accbuf[wv][q][rb];
            o0 += v.x; o1 += v.y;
        }
        o0 += bias[c0];
        o1 += bias[c0 + 1];

        // LayerNorm over 128 channels (2 per lane)
        float sred = o0 + o1;
        #pragma unroll
        for (int off = 1; off < 64; off <<= 1) sred += __shfl_xor(sred, off);
        float mu = sred * (1.f / 128.f);
        float d0 = o0 - mu, d1 = o1 - mu;
        float v = d0 * d0 + d1 * d1;
        #pragma unroll
        for (int off = 1; off < 64; off <<= 1) v += __shfl_xor(v, off);
        float rstd = rsqrtf(v * (1.f / 128.f) + 1e-5f);
        o0 = d0 * rstd * ln_g[c0] + ln_b[c0];
        o1 = d1 * rstd * ln_g[c0 + 1] + ln_b[c0 + 1];

        float2 hv = *(const float2*)&hin[(size_t)n * 128 + c0];
        if (FINAL) {
            float r0 = hv.x + o0, r1 = hv.y + o1;
            int g = n >> 9, rr = n & 511;
            if (rr < 511)
                *(float2*)&outp[((size_t)(g * 511 + rr)) * 128 + c0] = make_float2(r0, r1);
        } else {
            o0 = 0.5f * o0 * (1.f + erff(o0 * 0.70710678118f));   // exact GELU
            o1 = 0.5f * o1 * (1.f + erff(o1 * 0.70710678118f));
            hv.x += o0; hv.y += o1;
            *(float2*)&hout[(size_t)n * 128 + c0] = hv;
            uint pk = (uint)f2b(hv.x) | ((uint)f2b(hv.y) << 16);
            *(uint*)&hb[(size_t)n * 128 + c0] = pk;
        }
        __syncthreads();   // accbuf reuse guard before next node's writes (uniform)
    }
}

extern "C" void kernel_launch(void* const* d_in, const int* in_sizes, int n_in,
                              void* d_out, int out_size, void* d_ws, size_t ws_size,
                              hipStream_t stream) {
    const float* x        = (const float*)d_in[0];
    const int*   edge_src = (const int*)d_in[1];
    const int*   edge_dst = (const int*)d_in[2];
    const float* edge_attr= (const float*)d_in[3];
    const float* Wl       = (const float*)d_in[4];
    const float* bl       = (const float*)d_in[5];
    const float* Wr       = (const float*)d_in[6];
    const float* br       = (const float*)d_in[7];
    const float* We       = (const float*)d_in[8];
    const float* att      = (const float*)d_in[9];
    const float* bias_p   = (const float*)d_in[10];
    const float* ln_g     = (const float*)d_in[11];
    const float* ln_b     = (const float*)d_in[12];
    float* out = (float*)d_out;

    char* ws = (char*)d_ws;
    float*  h       = (float*)(ws + 0);                 // 33,554,432
    ushort* hb      = (ushort*)(ws + 33554432);         // 16,777,216
    ushort* xl      = (ushort*)(ws + 50331648);         // 16,777,216
    ushort* xr      = (ushort*)(ws + 67108864);         // 16,777,216
    int2*   adj     = (int2*)(ws + 83886080);           //  8,912,896
    int*    row_off = (int*)(ws + 92798976);            //    262,400 (incl pad)
    int*    cnt     = (int*)(ws + 93061376);            //    262,144 (also cursor)
    int*    bsum    = (int*)(ws + 93323520);            //      1,024
    float*  sumbuf  = (float*)(ws + 93324544);          //        256
    ushort* WT      = (ushort*)(ws + 93324800);         //    196,608 (3 layers x 2)

    // 1: transpose weights + zero cnt/sumbuf  (canary out[0]=100)
    k_init<<<dim3(128, 2, 3), 128, 0, stream>>>(Wl, Wr, WT, cnt, sumbuf, out);
    // 2: histogram + edge_attr sum            (canary out[1]=120)
    k_histsum<<<TOTE / 256, 256, 0, stream>>>(edge_dst, edge_attr, cnt, sumbuf, out);
    // 3-4: scan                               (canaries out[2]=140, out[3]=160)
    k_scanA<<<NN / 256, 256, 0, stream>>>(cnt, row_off, bsum, out);
    k_scanC<<<NN / 256, 256, 0, stream>>>(row_off, bsum, cnt, out);
    // 5: scatter (adj.x = src byte offset)    (canary out[4]=180)
    k_scatter<<<TOTE / 256, 256, 0, stream>>>(edge_src, edge_dst, edge_attr, sumbuf, cnt, adj, out);

    // layer 0: GEMM from fp32 x; residual from x   (canaries out[5]=200, out[6]=220)
    k_gemm<true><<<NN / 64, 256, 0, stream>>>(x, WT, bl, br, xl, xr, out, 5, 200.0f);
    k_attn<4, false><<<NN / 16, 128, 0, stream>>>(xl, xr, row_off, adj,
                                                  We, att, bias_p, ln_g, ln_b,
                                                  x, h, hb, nullptr, out, 6, 220.0f);
    // layer 1                                       (canaries out[7]=240, out[8]=260)
    k_gemm<false><<<NN / 64, 256, 0, stream>>>(hb, WT + 32768, bl + 128, br + 128, xl, xr, out, 7, 240.0f);
    k_attn<4, false><<<NN / 16, 128, 0, stream>>>(xl, xr, row_off, adj,
                                                  We + 128, att + 128, bias_p + 128,
                                                  ln_g + 128, ln_b + 128,
                                                  h, h, hb, nullptr, out, 8, 260.0f);
    // layer 2 (final): writes out directly, drops virtual node
    // (canary out[9]=280 from the gemm; final attn carries NO canary and
    //  overwrites out[0..9] with real values when it runs)
    k_gemm<false><<<NN / 64, 256, 0, stream>>>(hb, WT + 65536, bl + 256, br + 256, xl, xr, out, 9, 280.0f);
    k_attn<1, true><<<NN / 16, 128, 0, stream>>>(xl, xr, row_off, adj,
                                                 We + 256, att + 256, bias_p + 256,
                                                 ln_g + 256, ln_b + 256,
                                                 h, nullptr, nullptr, out, nullptr, 0, 0.0f);
}

// Round 10
// 652.700 us; speedup vs baseline: 2.6873x; 2.6873x over previous
//
#include <hip/hip_runtime.h>
#include <hip/hip_bf16.h>

typedef unsigned int uint;
typedef unsigned short ushort;

#define NN 65536
#define NE 1048576
#define DD 128
#define TOTE (NE + NN)   // 1114112

__device__ __forceinline__ float b2f(ushort u) {
    uint v = ((uint)u) << 16; float f; __builtin_memcpy(&f, &v, 4); return f;
}
__device__ __forceinline__ ushort f2b(float f) {
    uint x; __builtin_memcpy(&x, &f, 4);
    uint r = (x + 0x7fffu + ((x >> 16) & 1u)) >> 16;
    return (ushort)r;
}

typedef __bf16 bf16x8 __attribute__((ext_vector_type(8)));
typedef float f32x4 __attribute__((ext_vector_type(4)));
typedef float f32x2 __attribute__((ext_vector_type(2)));

// unpack 2 bf16 (packed in uint) -> packed float2, no cvt needed
__device__ __forceinline__ f32x2 bf2f2(uint u) {
    union { uint i; float f; } lo, hi;
    lo.i = u << 16; hi.i = u & 0xffff0000u;
    return (f32x2){lo.f, hi.f};
}

// Canary protocol (kept permanently; perf-free): each pre-final kernel writes a
// distinct constant into a distinct slot of out[0..9]; the FINAL k_attn
// overwrites them with real values. On a mid-pipeline failure, absmax decodes
// the last kernel that ran (100,120,...,280; bands disjoint vs max|ref|=6.5).

// ---------- init: transpose W (fp32 k-major -> bf16 n-major) + zero cnt/sumbuf ----------
__global__ void k_init(const float* __restrict__ Wl, const float* __restrict__ Wr,
                       ushort* __restrict__ WT, int* __restrict__ cnt, float* __restrict__ sumbuf,
                       float* __restrict__ cano) {
    if (cano && blockIdx.x == 0 && blockIdx.y == 0 && blockIdx.z == 0 && threadIdx.x == 0)
        cano[0] = 100.0f;
    // grid (128, 2, 3), block 128
    int k = blockIdx.x, n = threadIdx.x, lr = blockIdx.y, layer = blockIdx.z;
    const float* W = (lr ? Wr : Wl) + layer * 16384;
    WT[(layer * 2 + lr) * 16384 + n * 128 + k] = f2b(W[k * 128 + n]);
    int gid = ((blockIdx.z * 2 + blockIdx.y) * 128 + blockIdx.x) * 128 + threadIdx.x;
    if (gid < NN) cnt[gid] = 0;
    if (gid == NN) sumbuf[0] = 0.f;
}

// ---------- histogram by dst (+self loops) fused with edge_attr sum ----------
__global__ void k_histsum(const int* __restrict__ dst, const float* __restrict__ ea,
                          int* __restrict__ cnt, float* __restrict__ sum,
                          float* __restrict__ cano) {
    if (cano && blockIdx.x == 0 && threadIdx.x == 0) cano[1] = 120.0f;
    __shared__ float red[256];
    int t = threadIdx.x;
    int e = blockIdx.x * 256 + t;     // grid covers TOTE exactly
    int d = (e < NE) ? dst[e] : (e - NE);
    atomicAdd(&cnt[d], 1);
    float s = (e < NE) ? ea[e] : 0.f;
    red[t] = s; __syncthreads();
    for (int o = 128; o > 0; o >>= 1) { if (t < o) red[t] += red[t + o]; __syncthreads(); }
    if (t == 0 && red[0] != 0.f) atomicAdd(sum, red[0]);
}

__global__ void k_scanA(const int* __restrict__ cnt, int* __restrict__ row_off, int* __restrict__ bsum,
                        float* __restrict__ cano) {
    if (cano && blockIdx.x == 0 && threadIdx.x == 0) cano[2] = 140.0f;
    __shared__ int tmp[256];
    int t = threadIdx.x, i = blockIdx.x * 256 + t;
    int v = cnt[i]; tmp[t] = v; __syncthreads();
    for (int off = 1; off < 256; off <<= 1) {
        int x = (t >= off) ? tmp[t - off] : 0;
        __syncthreads();
        tmp[t] += x;
        __syncthreads();
    }
    row_off[i] = tmp[t] - v;
    if (t == 255) bsum[blockIdx.x] = tmp[255];
}

// scanC with local re-scan of bsum (eliminates scanB dispatch)
__global__ void k_scanC(int* __restrict__ row_off, const int* __restrict__ bsum, int* __restrict__ cursor,
                        float* __restrict__ cano) {
    if (cano && blockIdx.x == 0 && threadIdx.x == 0) cano[3] = 160.0f;
    __shared__ int tmp[256];
    __shared__ int excl[256];
    int t = threadIdx.x;
    int v = bsum[t]; tmp[t] = v; __syncthreads();
    for (int off = 1; off < 256; off <<= 1) {
        int x = (t >= off) ? tmp[t - off] : 0;
        __syncthreads();
        tmp[t] += x;
        __syncthreads();
    }
    excl[t] = tmp[t] - v;
    __syncthreads();
    int offb = excl[blockIdx.x];
    int i = blockIdx.x * 256 + t;
    int nv = row_off[i] + offb;
    row_off[i] = nv;
    cursor[i] = nv;
    if (i == 0) row_off[NN] = TOTE;
}

// adj.x stores src<<8 (byte offset into bf16 row array: src*128ch*2B)
__global__ void k_scatter(const int* __restrict__ src, const int* __restrict__ dst,
                          const float* __restrict__ ea, const float* __restrict__ sum,
                          int* __restrict__ cursor, int2* __restrict__ adj,
                          float* __restrict__ cano) {
    if (cano && blockIdx.x == 0 && threadIdx.x == 0) cano[4] = 180.0f;
    int e = blockIdx.x * 256 + threadIdx.x;
    int s, d; float a;
    if (e < NE) { s = src[e]; d = dst[e]; a = ea[e]; }
    else        { s = e - NE; d = s;      a = sum[0] * (1.0f / NE); }
    int pos = atomicAdd(&cursor[d], 1);
    adj[pos] = make_int2(s << 8, __float_as_int(a));
}

// ---------- dual GEMM: xl = src@Wl + bl, xr = src@Wr + br  (bf16 MFMA 16x16x32) ----------
#define LDA 136   // bf16 elems per A row in LDS (272B stride, 16B aligned)

template<bool F32SRC>
__global__ __launch_bounds__(256) void k_gemm(const void* __restrict__ srcv, const ushort* __restrict__ WT,
                                              const float* __restrict__ bl, const float* __restrict__ br,
                                              ushort* __restrict__ xl, ushort* __restrict__ xr,
                                              float* __restrict__ cano, int cslot, float cval) {
    if (cano && blockIdx.x == 0 && threadIdx.x == 0) cano[cslot] = cval;
    __shared__ ushort A[64 * LDA];
    int t = threadIdx.x;
    int rowbase = blockIdx.x * 64;

    if (F32SRC) {
        const float* src = (const float*)srcv;
        #pragma unroll
        for (int it = 0; it < 8; it++) {
            int idx = it * 256 + t;          // 2048 chunks of 4 floats
            int r = idx >> 5, cc = (idx & 31) * 4;
            float4 v = *(const float4*)&src[(size_t)(rowbase + r) * 128 + cc];
            ushort4 pk; pk.x = f2b(v.x); pk.y = f2b(v.y); pk.z = f2b(v.z); pk.w = f2b(v.w);
            *(ushort4*)&A[r * LDA + cc] = pk;
        }
    } else {
        const ushort* src = (const ushort*)srcv;
        #pragma unroll
        for (int it = 0; it < 4; it++) {
            int idx = it * 256 + t;          // 1024 chunks of 8 bf16
            int r = idx >> 4, cc = (idx & 15) * 8;
            *(bf16x8*)&A[r * LDA + cc] = *(const bf16x8*)&src[(size_t)(rowbase + r) * 128 + cc];
        }
    }
    __syncthreads();

    int wave = t >> 6, lane = t & 63;
    int row16 = lane & 15, quad = lane >> 4;

    f32x4 accl[8], accr[8];
    for (int i = 0; i < 8; i++) {
        accl[i] = (f32x4){0.f, 0.f, 0.f, 0.f};
        accr[i] = (f32x4){0.f, 0.f, 0.f, 0.f};
    }

    for (int ks = 0; ks < 4; ks++) {
        bf16x8 a = *(const bf16x8*)&A[(wave * 16 + row16) * LDA + ks * 32 + quad * 8];
        for (int tc = 0; tc < 8; tc++) {
            int coln = tc * 16 + row16;                 // B fragment: n = lane&15
            bf16x8 b_l = *(const bf16x8*)&WT[coln * 128 + ks * 32 + quad * 8];
            bf16x8 b_r = *(const bf16x8*)&WT[16384 + coln * 128 + ks * 32 + quad * 8];
            accl[tc] = __builtin_amdgcn_mfma_f32_16x16x32_bf16(a, b_l, accl[tc], 0, 0, 0);
            accr[tc] = __builtin_amdgcn_mfma_f32_16x16x32_bf16(a, b_r, accr[tc], 0, 0, 0);
        }
    }

    for (int tc = 0; tc < 8; tc++) {
        int col = tc * 16 + row16;                      // C/D: col = lane&15
        float bbl = bl[col], bbr = br[col];
        for (int r = 0; r < 4; r++) {
            int row = rowbase + wave * 16 + quad * 4 + r;   // C/D: row = quad*4 + reg
            size_t o = (size_t)row * 128 + col;
            xl[o] = f2b(accl[tc][r] + bbl);
            xr[o] = f2b(accr[tc][r] + bbr);
        }
    }
}

// ---------- fused attention: PERSISTENT waves + 4-group register prologue ----------
// Grid = NN/16 = 4096 blocks x 128 thr; each wave owns 8 CONTIGUOUS nodes
// (row_off chained; xr/hin reads L2-local); we2/at2 caches hoisted per wave.
// ROUND-9 LESSON: __launch_bounds__(128,8) capped VGPR at 64 -> the persistent
// loop's live state spilled to scratch (VGPR 32, FETCH 1.2GB, VALU 8%, 5x slower)
// even though occupancy hit 81% (confirming the churn theory). Use (128,4):
// only guarantees <=128 VGPR; round-8's identical body compiled to 64 under it.
// If <=64 regs -> 16 blocks/CU all resident (LDS 10240B x 16 = 160KiB exactly);
// if 65..128 -> 8/CU resident, one churn generation. Either way: NO SPILLS.
// Per node: 4-group prologue (verified +8% round 8): adj + xl-row loads for
// degree<=32 issued back-to-back -> one latency exposure; degree>32 tail serial.
// Lane = (p=lane>>3: edge slot, cl=lane&7: 16-ch block). accbuf stride 20 spreads
// banks. Barriers uniform across both waves (both loop exactly 8x).
template<int H, bool FINAL>
__global__ __launch_bounds__(128, 4) void k_attn(
    const ushort* __restrict__ xl, const ushort* __restrict__ xr,
    const int* __restrict__ row_off, const int2* __restrict__ adj,
    const float* __restrict__ We, const float* __restrict__ att,
    const float* __restrict__ bias, const float* __restrict__ ln_g, const float* __restrict__ ln_b,
    const float* __restrict__ hin, float* __restrict__ hout, ushort* __restrict__ hb,
    float* __restrict__ outp,
    float* __restrict__ cano, int cslot, float cval)
{
    if (cano && blockIdx.x == 0 && threadIdx.x == 0) cano[cslot] = cval;
    __shared__ float accbuf[2][8][160];   // [wave][p][cl*20 + 0..15] — bank-spread layout

    int wv = threadIdx.x >> 6, lane = threadIdx.x & 63;
    int gw = blockIdx.x * 2 + wv;        // global wave id, 0..8191
    int p = lane >> 3;          // edge slot within 8-edge group
    int cl = lane & 7;          // channel block: ch [16*cl, 16*cl+16)
    int c16 = cl * 16;
    const char* xlb = (const char*)xl;

    // register caches (packed pairs) — hoisted once per wave (8 nodes)
    f32x2 we2[8], at2[8];
    #pragma unroll
    for (int k = 0; k < 8; k++) {
        we2[k] = (f32x2){We[c16 + 2 * k], We[c16 + 2 * k + 1]};
        at2[k] = (f32x2){att[c16 + 2 * k], att[c16 + 2 * k + 1]};
    }
    int c0 = 2 * lane;
    int rb = (c0 >> 4) * 20 + (c0 & 15);

    int nbase = gw * 8;
    int sA = row_off[nbase];

    for (int nn = 0; nn < 8; ++nn) {
        int n = nbase + nn;
        int s1 = row_off[n + 1];
        int s0 = sA; sA = s1;            // chain: this node's end = next node's start

        // xr row for this node (packed pairs)
        f32x2 xrl2[8];
        {
            uint4 r0 = *(const uint4*)&xr[(size_t)n * 128 + c16];
            uint4 r1 = *(const uint4*)&xr[(size_t)n * 128 + c16 + 8];
            xrl2[0] = bf2f2(r0.x); xrl2[1] = bf2f2(r0.y); xrl2[2] = bf2f2(r0.z); xrl2[3] = bf2f2(r0.w);
            xrl2[4] = bf2f2(r1.x); xrl2[5] = bf2f2(r1.y); xrl2[6] = bf2f2(r1.z); xrl2[7] = bf2f2(r1.w);
        }

        int iters = (s1 - s0 + 7) >> 3;     // >= 1 (self-loop)

        float l_run = 0.f;
        f32x2 acc[8];
        #pragma unroll
        for (int k = 0; k < 8; k++) acc[k] = (f32x2){0.f, 0.f};

        // ---- 4-group register prologue: issue all adj loads, then all gathers ----
        int j0 = s0 + p,      j1 = s0 + 8 + p,  j2 = s0 + 16 + p, j3 = s0 + 24 + p;
        int i0 = (j0 < s1) ? j0 : s0;
        int i1 = (j1 < s1) ? j1 : s0;
        int i2 = (j2 < s1) ? j2 : s0;
        int i3 = (j3 < s1) ? j3 : s0;
        int2 a0 = adj[i0], a1 = adj[i1], a2 = adj[i2], a3 = adj[i3];
        float ea0 = (j0 < s1) ? __int_as_float(a0.y) : 0.f;
        float ea1 = (j1 < s1) ? __int_as_float(a1.y) : 0.f;
        float ea2v = (j2 < s1) ? __int_as_float(a2.y) : 0.f;
        float ea3 = (j3 < s1) ? __int_as_float(a3.y) : 0.f;
        const char* q0 = xlb + (size_t)(uint)a0.x + (cl << 5);
        const char* q1 = xlb + (size_t)(uint)a1.x + (cl << 5);
        const char* q2 = xlb + (size_t)(uint)a2.x + (cl << 5);
        const char* q3 = xlb + (size_t)(uint)a3.x + (cl << 5);
        uint4 u00 = *(const uint4*)q0, u01 = *(const uint4*)(q0 + 16);
        uint4 u10 = *(const uint4*)q1, u11 = *(const uint4*)(q1 + 16);
        uint4 u20 = *(const uint4*)q2, u21 = *(const uint4*)(q2 + 16);
        uint4 u30 = *(const uint4*)q3, u31 = *(const uint4*)(q3 + 16);

        // consume one 8-edge group held in registers (identical math to baseline)
        auto consume = [&](uint4 u0, uint4 u1, float ea_c, int itx) {
            bool valid = (s0 + itx * 8 + p) < s1;
            f32x2 xf[8];
            xf[0] = bf2f2(u0.x); xf[1] = bf2f2(u0.y); xf[2] = bf2f2(u0.z); xf[3] = bf2f2(u0.w);
            xf[4] = bf2f2(u1.x); xf[5] = bf2f2(u1.y); xf[6] = bf2f2(u1.z); xf[7] = bf2f2(u1.w);

            f32x2 ea2 = (f32x2){ea_c, ea_c};
            f32x2 s2 = (f32x2){0.f, 0.f};
            #pragma unroll
            for (int k = 0; k < 8; k++) {
                f32x2 m = xf[k] + __builtin_elementwise_fma(ea2, we2[k], xrl2[k]);
                m = __builtin_elementwise_max(m, 0.2f * m);     // leaky_relu(0.2)
                s2 = __builtin_elementwise_fma(m, at2[k], s2);
            }
            float s = s2.x + s2.y;
            // head reduction across cl lanes of same edge
            s += __shfl_xor(s, 1);
            if (H == 1) { s += __shfl_xor(s, 2); s += __shfl_xor(s, 4); }
            if (!valid) s = -1e30f;

            float e = __expf(s);                 // 0 for invalid; no overflow (|s| small)
            l_run += e;
            f32x2 e2 = (f32x2){e, e};
            #pragma unroll
            for (int k = 0; k < 8; k++) acc[k] = __builtin_elementwise_fma(e2, xf[k], acc[k]);
        };

        consume(u00, u01, ea0, 0);
        if (iters > 1) consume(u10, u11, ea1, 1);
        if (iters > 2) consume(u20, u21, ea2v, 2);
        if (iters > 3) consume(u30, u31, ea3, 3);
        // rare tail: degree > 32 (~0.03% of nodes), simple serial loads
        for (int it = 4; it < iters; ++it) {
            int jn = s0 + it * 8 + p;
            int jb = (jn < s1) ? jn : s0;
            int2 pk = adj[jb];
            float ean = (jn < s1) ? __int_as_float(pk.y) : 0.f;
            const char* rp = xlb + (size_t)(uint)pk.x + (cl << 5);
            uint4 nu0 = *(const uint4*)rp;
            uint4 nu1 = *(const uint4*)(rp + 16);
            consume(nu0, nu1, ean, it);
        }

        // per-head denominator over the 8 edge slots (p)
        l_run += __shfl_xor(l_run, 8);
        l_run += __shfl_xor(l_run, 16);
        l_run += __shfl_xor(l_run, 32);
        float inv = 1.0f / (l_run + 1e-16f);     // matches this lane's channels' head

        // write inv-premultiplied partials to LDS tile (bank-spread: base cl*20)
        float* row = &accbuf[wv][p][cl * 20];
        #pragma unroll
        for (int i = 0; i < 4; i++)
            *(float4*)&row[4 * i] = make_float4(acc[2 * i].x * inv, acc[2 * i].y * inv,
                                                acc[2 * i + 1].x * inv, acc[2 * i + 1].y * inv);
        __syncthreads();

        // each lane sums its 2 channels across the 8 p-slots
        float o0 = 0.f, o1 = 0.f;
        #pragma unroll
        for (int q = 0; q < 8; q++) {
            float2 v = *(float2*)&accbuf[wv][q][rb];
            o0 += v.x; o1 += v.y;
        }
        o0 += bias[c0];
        o1 += bias[c0 + 1];

        // LayerNorm over 128 channels (2 per lane)
        float sred = o0 + o1;
        #pragma unroll
        for (int off = 1; off < 64; off <<= 1) sred += __shfl_xor(sred, off);
        float mu = sred * (1.f / 128.f);
        float d0 = o0 - mu, d1 = o1 - mu;
        float v = d0 * d0 + d1 * d1;
        #pragma unroll
        for (int off = 1; off < 64; off <<= 1) v += __shfl_xor(v, off);
        float rstd = rsqrtf(v * (1.f / 128.f) + 1e-5f);
        o0 = d0 * rstd * ln_g[c0] + ln_b[c0];
        o1 = d1 * rstd * ln_g[c0 + 1] + ln_b[c0 + 1];

        float2 hv = *(const float2*)&hin[(size_t)n * 128 + c0];
        if (FINAL) {
            float r0 = hv.x + o0, r1 = hv.y + o1;
            int g = n >> 9, rr = n & 511;
            if (rr < 511)
                *(float2*)&outp[((size_t)(g * 511 + rr)) * 128 + c0] = make_float2(r0, r1);
        } else {
            o0 = 0.5f * o0 * (1.f + erff(o0 * 0.70710678118f));   // exact GELU
            o1 = 0.5f * o1 * (1.f + erff(o1 * 0.70710678118f));
            hv.x += o0; hv.y += o1;
            *(float2*)&hout[(size_t)n * 128 + c0] = hv;
            uint pk = (uint)f2b(hv.x) | ((uint)f2b(hv.y) << 16);
            *(uint*)&hb[(size_t)n * 128 + c0] = pk;
        }
        __syncthreads();   // accbuf reuse guard before next node's writes (uniform)
    }
}

extern "C" void kernel_launch(void* const* d_in, const int* in_sizes, int n_in,
                              void* d_out, int out_size, void* d_ws, size_t ws_size,
                              hipStream_t stream) {
    const float* x        = (const float*)d_in[0];
    const int*   edge_src = (const int*)d_in[1];
    const int*   edge_dst = (const int*)d_in[2];
    const float* edge_attr= (const float*)d_in[3];
    const float* Wl       = (const float*)d_in[4];
    const float* bl       = (const float*)d_in[5];
    const float* Wr       = (const float*)d_in[6];
    const float* br       = (const float*)d_in[7];
    const float* We       = (const float*)d_in[8];
    const float* att      = (const float*)d_in[9];
    const float* bias_p   = (const float*)d_in[10];
    const float* ln_g     = (const float*)d_in[11];
    const float* ln_b     = (const float*)d_in[12];
    float* out = (float*)d_out;

    char* ws = (char*)d_ws;
    float*  h       = (float*)(ws + 0);                 // 33,554,432
    ushort* hb      = (ushort*)(ws + 33554432);         // 16,777,216
    ushort* xl      = (ushort*)(ws + 50331648);         // 16,777,216
    ushort* xr      = (ushort*)(ws + 67108864);         // 16,777,216
    int2*   adj     = (int2*)(ws + 83886080);           //  8,912,896
    int*    row_off = (int*)(ws + 92798976);            //    262,400 (incl pad)
    int*    cnt     = (int*)(ws + 93061376);            //    262,144 (also cursor)
    int*    bsum    = (int*)(ws + 93323520);            //      1,024
    float*  sumbuf  = (float*)(ws + 93324544);          //        256
    ushort* WT      = (ushort*)(ws + 93324800);         //    196,608 (3 layers x 2)

    // 1: transpose weights + zero cnt/sumbuf  (canary out[0]=100)
    k_init<<<dim3(128, 2, 3), 128, 0, stream>>>(Wl, Wr, WT, cnt, sumbuf, out);
    // 2: histogram + edge_attr sum            (canary out[1]=120)
    k_histsum<<<TOTE / 256, 256, 0, stream>>>(edge_dst, edge_attr, cnt, sumbuf, out);
    // 3-4: scan                               (canaries out[2]=140, out[3]=160)
    k_scanA<<<NN / 256, 256, 0, stream>>>(cnt, row_off, bsum, out);
    k_scanC<<<NN / 256, 256, 0, stream>>>(row_off, bsum, cnt, out);
    // 5: scatter (adj.x = src byte offset)    (canary out[4]=180)
    k_scatter<<<TOTE / 256, 256, 0, stream>>>(edge_src, edge_dst, edge_attr, sumbuf, cnt, adj, out);

    // layer 0: GEMM from fp32 x; residual from x   (canaries out[5]=200, out[6]=220)
    k_gemm<true><<<NN / 64, 256, 0, stream>>>(x, WT, bl, br, xl, xr, out, 5, 200.0f);
    k_attn<4, false><<<NN / 16, 128, 0, stream>>>(xl, xr, row_off, adj,
                                                  We, att, bias_p, ln_g, ln_b,
                                                  x, h, hb, nullptr, out, 6, 220.0f);
    // layer 1                                       (canaries out[7]=240, out[8]=260)
    k_gemm<false><<<NN / 64, 256, 0, stream>>>(hb, WT + 32768, bl + 128, br + 128, xl, xr, out, 7, 240.0f);
    k_attn<4, false><<<NN / 16, 128, 0, stream>>>(xl, xr, row_off, adj,
                                                  We + 128, att + 128, bias_p + 128,
                                                  ln_g + 128, ln_b + 128,
                                                  h, h, hb, nullptr, out, 8, 260.0f);
    // layer 2 (final): writes out directly, drops virtual node
    // (canary out[9]=280 from the gemm; final attn carries NO canary and
    //  overwrites out[0..9] with real values when it runs)
    k_gemm<false><<<NN / 64, 256, 0, stream>>>(hb, WT + 65536, bl + 256, br + 256, xl, xr, out, 9, 280.0f);
    k_attn<1, true><<<NN / 16, 128, 0, stream>>>(xl, xr, row_off, adj,
                                                 We + 256, att + 256, bias_p + 256,
                                                 ln_g + 256, ln_b + 256,
                                                 h, nullptr, nullptr, out, nullptr, 0, 0.0f);
}

// Round 11
// 617.355 us; speedup vs baseline: 2.8411x; 1.0573x over previous
//
#include <hip/hip_runtime.h>
#include <hip/hip_bf16.h>

typedef unsigned int uint;
typedef unsigned short ushort;

#define NN 65536
#define NE 1048576
#define DD 128
#define TOTE (NE + NN)   // 1114112

__device__ __forceinline__ float b2f(ushort u) {
    uint v = ((uint)u) << 16; float f; __builtin_memcpy(&f, &v, 4); return f;
}
__device__ __forceinline__ ushort f2b(float f) {
    uint x; __builtin_memcpy(&x, &f, 4);
    uint r = (x + 0x7fffu + ((x >> 16) & 1u)) >> 16;
    return (ushort)r;
}

typedef __bf16 bf16x8 __attribute__((ext_vector_type(8)));
typedef float f32x4 __attribute__((ext_vector_type(4)));
typedef float f32x2 __attribute__((ext_vector_type(2)));

// unpack 2 bf16 (packed in uint) -> packed float2, no cvt needed
__device__ __forceinline__ f32x2 bf2f2(uint u) {
    union { uint i; float f; } lo, hi;
    lo.i = u << 16; hi.i = u & 0xffff0000u;
    return (f32x2){lo.f, hi.f};
}

// Canary protocol (kept permanently; perf-free): each pre-final kernel writes a
// distinct constant into a distinct slot of out[0..9]; the FINAL k_attn
// overwrites them with real values. On a mid-pipeline failure, absmax decodes
// the last kernel that ran (100,120,...,280; bands disjoint vs max|ref|=6.5).

// ---------- init: transpose W (fp32 k-major -> bf16 n-major) + zero cnt/sumbuf ----------
__global__ void k_init(const float* __restrict__ Wl, const float* __restrict__ Wr,
                       ushort* __restrict__ WT, int* __restrict__ cnt, float* __restrict__ sumbuf,
                       float* __restrict__ cano) {
    if (cano && blockIdx.x == 0 && blockIdx.y == 0 && blockIdx.z == 0 && threadIdx.x == 0)
        cano[0] = 100.0f;
    // grid (128, 2, 3), block 128
    int k = blockIdx.x, n = threadIdx.x, lr = blockIdx.y, layer = blockIdx.z;
    const float* W = (lr ? Wr : Wl) + layer * 16384;
    WT[(layer * 2 + lr) * 16384 + n * 128 + k] = f2b(W[k * 128 + n]);
    int gid = ((blockIdx.z * 2 + blockIdx.y) * 128 + blockIdx.x) * 128 + threadIdx.x;
    if (gid < NN) cnt[gid] = 0;
    if (gid == NN) sumbuf[0] = 0.f;
}

// ---------- histogram by dst (+self loops) fused with edge_attr sum ----------
__global__ void k_histsum(const int* __restrict__ dst, const float* __restrict__ ea,
                          int* __restrict__ cnt, float* __restrict__ sum,
                          float* __restrict__ cano) {
    if (cano && blockIdx.x == 0 && threadIdx.x == 0) cano[1] = 120.0f;
    __shared__ float red[256];
    int t = threadIdx.x;
    int e = blockIdx.x * 256 + t;     // grid covers TOTE exactly
    int d = (e < NE) ? dst[e] : (e - NE);
    atomicAdd(&cnt[d], 1);
    float s = (e < NE) ? ea[e] : 0.f;
    red[t] = s; __syncthreads();
    for (int o = 128; o > 0; o >>= 1) { if (t < o) red[t] += red[t + o]; __syncthreads(); }
    if (t == 0 && red[0] != 0.f) atomicAdd(sum, red[0]);
}

__global__ void k_scanA(const int* __restrict__ cnt, int* __restrict__ row_off, int* __restrict__ bsum,
                        float* __restrict__ cano) {
    if (cano && blockIdx.x == 0 && threadIdx.x == 0) cano[2] = 140.0f;
    __shared__ int tmp[256];
    int t = threadIdx.x, i = blockIdx.x * 256 + t;
    int v = cnt[i]; tmp[t] = v; __syncthreads();
    for (int off = 1; off < 256; off <<= 1) {
        int x = (t >= off) ? tmp[t - off] : 0;
        __syncthreads();
        tmp[t] += x;
        __syncthreads();
    }
    row_off[i] = tmp[t] - v;
    if (t == 255) bsum[blockIdx.x] = tmp[255];
}

// scanC with local re-scan of bsum (eliminates scanB dispatch)
__global__ void k_scanC(int* __restrict__ row_off, const int* __restrict__ bsum, int* __restrict__ cursor,
                        float* __restrict__ cano) {
    if (cano && blockIdx.x == 0 && threadIdx.x == 0) cano[3] = 160.0f;
    __shared__ int tmp[256];
    __shared__ int excl[256];
    int t = threadIdx.x;
    int v = bsum[t]; tmp[t] = v; __syncthreads();
    for (int off = 1; off < 256; off <<= 1) {
        int x = (t >= off) ? tmp[t - off] : 0;
        __syncthreads();
        tmp[t] += x;
        __syncthreads();
    }
    excl[t] = tmp[t] - v;
    __syncthreads();
    int offb = excl[blockIdx.x];
    int i = blockIdx.x * 256 + t;
    int nv = row_off[i] + offb;
    row_off[i] = nv;
    cursor[i] = nv;
    if (i == 0) row_off[NN] = TOTE;
}

// adj.x stores src<<8 (byte offset into bf16 row array: src*128ch*2B)
__global__ void k_scatter(const int* __restrict__ src, const int* __restrict__ dst,
                          const float* __restrict__ ea, const float* __restrict__ sum,
                          int* __restrict__ cursor, int2* __restrict__ adj,
                          float* __restrict__ cano) {
    if (cano && blockIdx.x == 0 && threadIdx.x == 0) cano[4] = 180.0f;
    int e = blockIdx.x * 256 + threadIdx.x;
    int s, d; float a;
    if (e < NE) { s = src[e]; d = dst[e]; a = ea[e]; }
    else        { s = e - NE; d = s;      a = sum[0] * (1.0f / NE); }
    int pos = atomicAdd(&cursor[d], 1);
    adj[pos] = make_int2(s << 8, __float_as_int(a));
}

// ---------- dual GEMM: xl = src@Wl + bl, xr = src@Wr + br  (bf16 MFMA 16x16x32) ----------
#define LDA 136   // bf16 elems per A row in LDS (272B stride, 16B aligned)

template<bool F32SRC>
__global__ __launch_bounds__(256) void k_gemm(const void* __restrict__ srcv, const ushort* __restrict__ WT,
                                              const float* __restrict__ bl, const float* __restrict__ br,
                                              ushort* __restrict__ xl, ushort* __restrict__ xr,
                                              float* __restrict__ cano, int cslot, float cval) {
    if (cano && blockIdx.x == 0 && threadIdx.x == 0) cano[cslot] = cval;
    __shared__ ushort A[64 * LDA];
    int t = threadIdx.x;
    int rowbase = blockIdx.x * 64;

    if (F32SRC) {
        const float* src = (const float*)srcv;
        #pragma unroll
        for (int it = 0; it < 8; it++) {
            int idx = it * 256 + t;          // 2048 chunks of 4 floats
            int r = idx >> 5, cc = (idx & 31) * 4;
            float4 v = *(const float4*)&src[(size_t)(rowbase + r) * 128 + cc];
            ushort4 pk; pk.x = f2b(v.x); pk.y = f2b(v.y); pk.z = f2b(v.z); pk.w = f2b(v.w);
            *(ushort4*)&A[r * LDA + cc] = pk;
        }
    } else {
        const ushort* src = (const ushort*)srcv;
        #pragma unroll
        for (int it = 0; it < 4; it++) {
            int idx = it * 256 + t;          // 1024 chunks of 8 bf16
            int r = idx >> 4, cc = (idx & 15) * 8;
            *(bf16x8*)&A[r * LDA + cc] = *(const bf16x8*)&src[(size_t)(rowbase + r) * 128 + cc];
        }
    }
    __syncthreads();

    int wave = t >> 6, lane = t & 63;
    int row16 = lane & 15, quad = lane >> 4;

    f32x4 accl[8], accr[8];
    for (int i = 0; i < 8; i++) {
        accl[i] = (f32x4){0.f, 0.f, 0.f, 0.f};
        accr[i] = (f32x4){0.f, 0.f, 0.f, 0.f};
    }

    for (int ks = 0; ks < 4; ks++) {
        bf16x8 a = *(const bf16x8*)&A[(wave * 16 + row16) * LDA + ks * 32 + quad * 8];
        for (int tc = 0; tc < 8; tc++) {
            int coln = tc * 16 + row16;                 // B fragment: n = lane&15
            bf16x8 b_l = *(const bf16x8*)&WT[coln * 128 + ks * 32 + quad * 8];
            bf16x8 b_r = *(const bf16x8*)&WT[16384 + coln * 128 + ks * 32 + quad * 8];
            accl[tc] = __builtin_amdgcn_mfma_f32_16x16x32_bf16(a, b_l, accl[tc], 0, 0, 0);
            accr[tc] = __builtin_amdgcn_mfma_f32_16x16x32_bf16(a, b_r, accr[tc], 0, 0, 0);
        }
    }

    for (int tc = 0; tc < 8; tc++) {
        int col = tc * 16 + row16;                      // C/D: col = lane&15
        float bbl = bl[col], bbr = br[col];
        for (int r = 0; r < 4; r++) {
            int row = rowbase + wave * 16 + quad * 4 + r;   // C/D: row = quad*4 + reg
            size_t o = (size_t)row * 128 + col;
            xl[o] = f2b(accl[tc][r] + bbl);
            xr[o] = f2b(accr[tc][r] + bbr);
        }
    }
}

// ---------- fused attention: 4-wave blocks + 4-group register prologue ----------
// ROUND-10 LESSON: persistent 8-node waves regressed (108.7us; lost MLP+locality,
// FETCH +28%) despite full static residency -> reverted to R8 structure (88us).
// ROUND-8 DIAGNOSIS REFINED: resident waves = block-arrival-rate x lifetime x
// waves/block (R8: 372 blocks/us x 2.7us x 2 = ~8 waves/CU = the measured 40%).
// THIS ROUND: raise the waves/block term only — 256-thr block = 4 waves, each
// wave ONE node (identical per-wave code path to R8). Block count halves to
// 16384; lifetime unchanged -> predicted resident waves ~2x.
// LDS: accbuf[4][8][160]x4B = 20480B -> 8 blocks/CU cap = 32 waves. OK.
// __launch_bounds__(256,4): 128-VGPR ceiling (body compiles to 64 under it; the
// prior (256,8) spill and our R9 disaster were both the 64-cap at min-waves=8).
// Per node: 4-group prologue (verified +8% R8): adj + xl-row loads for degree<=32
// issued back-to-back -> one latency exposure; degree>32 tail serial. Clamped
// slots re-read adj[s0], masked via valid -> logit -1e30 -> e=0.
// Lane = (p=lane>>3: edge slot, cl=lane&7: 16-ch block). accbuf stride 20
// spreads the 8 cl lanes across all 32 banks.
template<int H, bool FINAL>
__global__ __launch_bounds__(256, 4) void k_attn(
    const ushort* __restrict__ xl, const ushort* __restrict__ xr,
    const int* __restrict__ row_off, const int2* __restrict__ adj,
    const float* __restrict__ We, const float* __restrict__ att,
    const float* __restrict__ bias, const float* __restrict__ ln_g, const float* __restrict__ ln_b,
    const float* __restrict__ hin, float* __restrict__ hout, ushort* __restrict__ hb,
    float* __restrict__ outp,
    float* __restrict__ cano, int cslot, float cval)
{
    if (cano && blockIdx.x == 0 && threadIdx.x == 0) cano[cslot] = cval;
    __shared__ float accbuf[4][8][160];   // [wave][p][cl*20 + 0..15] — bank-spread layout

    int wv = threadIdx.x >> 6, lane = threadIdx.x & 63;
    int n = blockIdx.x * 4 + wv;
    int p = lane >> 3;          // edge slot within 8-edge group
    int cl = lane & 7;          // channel block: ch [16*cl, 16*cl+16)
    int c16 = cl * 16;
    const char* xlb = (const char*)xl;

    // register caches (packed pairs)
    f32x2 we2[8], at2[8], xrl2[8];
    #pragma unroll
    for (int k = 0; k < 8; k++) {
        we2[k] = (f32x2){We[c16 + 2 * k], We[c16 + 2 * k + 1]};
        at2[k] = (f32x2){att[c16 + 2 * k], att[c16 + 2 * k + 1]};
    }
    {
        uint4 r0 = *(const uint4*)&xr[(size_t)n * 128 + c16];
        uint4 r1 = *(const uint4*)&xr[(size_t)n * 128 + c16 + 8];
        xrl2[0] = bf2f2(r0.x); xrl2[1] = bf2f2(r0.y); xrl2[2] = bf2f2(r0.z); xrl2[3] = bf2f2(r0.w);
        xrl2[4] = bf2f2(r1.x); xrl2[5] = bf2f2(r1.y); xrl2[6] = bf2f2(r1.z); xrl2[7] = bf2f2(r1.w);
    }

    int s0 = row_off[n], s1 = row_off[n + 1];
    int iters = (s1 - s0 + 7) >> 3;     // >= 1 (self-loop)

    float l_run = 0.f;
    f32x2 acc[8];
    #pragma unroll
    for (int k = 0; k < 8; k++) acc[k] = (f32x2){0.f, 0.f};

    // ---- 4-group register prologue: issue all adj loads, then all gathers ----
    int j0 = s0 + p,      j1 = s0 + 8 + p,  j2 = s0 + 16 + p, j3 = s0 + 24 + p;
    int i0 = (j0 < s1) ? j0 : s0;
    int i1 = (j1 < s1) ? j1 : s0;
    int i2 = (j2 < s1) ? j2 : s0;
    int i3 = (j3 < s1) ? j3 : s0;
    int2 a0 = adj[i0], a1 = adj[i1], a2 = adj[i2], a3 = adj[i3];
    float ea0 = (j0 < s1) ? __int_as_float(a0.y) : 0.f;
    float ea1 = (j1 < s1) ? __int_as_float(a1.y) : 0.f;
    float ea2v = (j2 < s1) ? __int_as_float(a2.y) : 0.f;
    float ea3 = (j3 < s1) ? __int_as_float(a3.y) : 0.f;
    const char* q0 = xlb + (size_t)(uint)a0.x + (cl << 5);
    const char* q1 = xlb + (size_t)(uint)a1.x + (cl << 5);
    const char* q2 = xlb + (size_t)(uint)a2.x + (cl << 5);
    const char* q3 = xlb + (size_t)(uint)a3.x + (cl << 5);
    uint4 u00 = *(const uint4*)q0, u01 = *(const uint4*)(q0 + 16);
    uint4 u10 = *(const uint4*)q1, u11 = *(const uint4*)(q1 + 16);
    uint4 u20 = *(const uint4*)q2, u21 = *(const uint4*)(q2 + 16);
    uint4 u30 = *(const uint4*)q3, u31 = *(const uint4*)(q3 + 16);

    // consume one 8-edge group held in registers (identical math to baseline)
    auto consume = [&](uint4 u0, uint4 u1, float ea_c, int itx) {
        bool valid = (s0 + itx * 8 + p) < s1;
        f32x2 xf[8];
        xf[0] = bf2f2(u0.x); xf[1] = bf2f2(u0.y); xf[2] = bf2f2(u0.z); xf[3] = bf2f2(u0.w);
        xf[4] = bf2f2(u1.x); xf[5] = bf2f2(u1.y); xf[6] = bf2f2(u1.z); xf[7] = bf2f2(u1.w);

        f32x2 ea2 = (f32x2){ea_c, ea_c};
        f32x2 s2 = (f32x2){0.f, 0.f};
        #pragma unroll
        for (int k = 0; k < 8; k++) {
            f32x2 m = xf[k] + __builtin_elementwise_fma(ea2, we2[k], xrl2[k]);
            m = __builtin_elementwise_max(m, 0.2f * m);     // leaky_relu(0.2)
            s2 = __builtin_elementwise_fma(m, at2[k], s2);
        }
        float s = s2.x + s2.y;
        // head reduction across cl lanes of same edge
        s += __shfl_xor(s, 1);
        if (H == 1) { s += __shfl_xor(s, 2); s += __shfl_xor(s, 4); }
        if (!valid) s = -1e30f;

        float e = __expf(s);                 // 0 for invalid; no overflow (|s| small)
        l_run += e;
        f32x2 e2 = (f32x2){e, e};
        #pragma unroll
        for (int k = 0; k < 8; k++) acc[k] = __builtin_elementwise_fma(e2, xf[k], acc[k]);
    };

    consume(u00, u01, ea0, 0);
    if (iters > 1) consume(u10, u11, ea1, 1);
    if (iters > 2) consume(u20, u21, ea2v, 2);
    if (iters > 3) consume(u30, u31, ea3, 3);
    // rare tail: degree > 32 (~0.03% of nodes), simple serial loads
    for (int it = 4; it < iters; ++it) {
        int jn = s0 + it * 8 + p;
        int jb = (jn < s1) ? jn : s0;
        int2 pk = adj[jb];
        float ean = (jn < s1) ? __int_as_float(pk.y) : 0.f;
        const char* rp = xlb + (size_t)(uint)pk.x + (cl << 5);
        uint4 nu0 = *(const uint4*)rp;
        uint4 nu1 = *(const uint4*)(rp + 16);
        consume(nu0, nu1, ean, it);
    }

    // per-head denominator over the 8 edge slots (p)
    l_run += __shfl_xor(l_run, 8);
    l_run += __shfl_xor(l_run, 16);
    l_run += __shfl_xor(l_run, 32);
    float inv = 1.0f / (l_run + 1e-16f);     // matches this lane's channels' head

    // write inv-premultiplied partials to LDS tile (bank-spread: base cl*20)
    float* row = &accbuf[wv][p][cl * 20];
    #pragma unroll
    for (int i = 0; i < 4; i++)
        *(float4*)&row[4 * i] = make_float4(acc[2 * i].x * inv, acc[2 * i].y * inv,
                                            acc[2 * i + 1].x * inv, acc[2 * i + 1].y * inv);
    __syncthreads();

    // each lane sums its 2 channels across the 8 p-slots
    int c0 = 2 * lane;
    int rb = (c0 >> 4) * 20 + (c0 & 15);
    float o0 = 0.f, o1 = 0.f;
    #pragma unroll
    for (int q = 0; q < 8; q++) {
        float2 v = *(float2*)&accbuf[wv][q][rb];
        o0 += v.x; o1 += v.y;
    }
    o0 += bias[c0];
    o1 += bias[c0 + 1];

    // LayerNorm over 128 channels (2 per lane)
    float sred = o0 + o1;
    #pragma unroll
    for (int off = 1; off < 64; off <<= 1) sred += __shfl_xor(sred, off);
    float mu = sred * (1.f / 128.f);
    float d0 = o0 - mu, d1 = o1 - mu;
    float v = d0 * d0 + d1 * d1;
    #pragma unroll
    for (int off = 1; off < 64; off <<= 1) v += __shfl_xor(v, off);
    float rstd = rsqrtf(v * (1.f / 128.f) + 1e-5f);
    o0 = d0 * rstd * ln_g[c0] + ln_b[c0];
    o1 = d1 * rstd * ln_g[c0 + 1] + ln_b[c0 + 1];

    float2 hv = *(const float2*)&hin[(size_t)n * 128 + c0];
    if (FINAL) {
        float r0 = hv.x + o0, r1 = hv.y + o1;
        int g = n >> 9, rr = n & 511;
        if (rr < 511)
            *(float2*)&outp[((size_t)(g * 511 + rr)) * 128 + c0] = make_float2(r0, r1);
    } else {
        o0 = 0.5f * o0 * (1.f + erff(o0 * 0.70710678118f));   // exact GELU
        o1 = 0.5f * o1 * (1.f + erff(o1 * 0.70710678118f));
        hv.x += o0; hv.y += o1;
        *(float2*)&hout[(size_t)n * 128 + c0] = hv;
        uint pk = (uint)f2b(hv.x) | ((uint)f2b(hv.y) << 16);
        *(uint*)&hb[(size_t)n * 128 + c0] = pk;
    }
}

extern "C" void kernel_launch(void* const* d_in, const int* in_sizes, int n_in,
                              void* d_out, int out_size, void* d_ws, size_t ws_size,
                              hipStream_t stream) {
    const float* x        = (const float*)d_in[0];
    const int*   edge_src = (const int*)d_in[1];
    const int*   edge_dst = (const int*)d_in[2];
    const float* edge_attr= (const float*)d_in[3];
    const float* Wl       = (const float*)d_in[4];
    const float* bl       = (const float*)d_in[5];
    const float* Wr       = (const float*)d_in[6];
    const float* br       = (const float*)d_in[7];
    const float* We       = (const float*)d_in[8];
    const float* att      = (const float*)d_in[9];
    const float* bias_p   = (const float*)d_in[10];
    const float* ln_g     = (const float*)d_in[11];
    const float* ln_b     = (const float*)d_in[12];
    float* out = (float*)d_out;

    char* ws = (char*)d_ws;
    float*  h       = (float*)(ws + 0);                 // 33,554,432
    ushort* hb      = (ushort*)(ws + 33554432);         // 16,777,216
    ushort* xl      = (ushort*)(ws + 50331648);         // 16,777,216
    ushort* xr      = (ushort*)(ws + 67108864);         // 16,777,216
    int2*   adj     = (int2*)(ws + 83886080);           //  8,912,896
    int*    row_off = (int*)(ws + 92798976);            //    262,400 (incl pad)
    int*    cnt     = (int*)(ws + 93061376);            //    262,144 (also cursor)
    int*    bsum    = (int*)(ws + 93323520);            //      1,024
    float*  sumbuf  = (float*)(ws + 93324544);          //        256
    ushort* WT      = (ushort*)(ws + 93324800);         //    196,608 (3 layers x 2)

    // 1: transpose weights + zero cnt/sumbuf  (canary out[0]=100)
    k_init<<<dim3(128, 2, 3), 128, 0, stream>>>(Wl, Wr, WT, cnt, sumbuf, out);
    // 2: histogram + edge_attr sum            (canary out[1]=120)
    k_histsum<<<TOTE / 256, 256, 0, stream>>>(edge_dst, edge_attr, cnt, sumbuf, out);
    // 3-4: scan                               (canaries out[2]=140, out[3]=160)
    k_scanA<<<NN / 256, 256, 0, stream>>>(cnt, row_off, bsum, out);
    k_scanC<<<NN / 256, 256, 0, stream>>>(row_off, bsum, cnt, out);
    // 5: scatter (adj.x = src byte offset)    (canary out[4]=180)
    k_scatter<<<TOTE / 256, 256, 0, stream>>>(edge_src, edge_dst, edge_attr, sumbuf, cnt, adj, out);

    // layer 0: GEMM from fp32 x; residual from x   (canaries out[5]=200, out[6]=220)
    k_gemm<true><<<NN / 64, 256, 0, stream>>>(x, WT, bl, br, xl, xr, out, 5, 200.0f);
    k_attn<4, false><<<NN / 4, 256, 0, stream>>>(xl, xr, row_off, adj,
                                                 We, att, bias_p, ln_g, ln_b,
                                                 x, h, hb, nullptr, out, 6, 220.0f);
    // layer 1                                       (canaries out[7]=240, out[8]=260)
    k_gemm<false><<<NN / 64, 256, 0, stream>>>(hb, WT + 32768, bl + 128, br + 128, xl, xr, out, 7, 240.0f);
    k_attn<4, false><<<NN / 4, 256, 0, stream>>>(xl, xr, row_off, adj,
                                                 We + 128, att + 128, bias_p + 128,
                                                 ln_g + 128, ln_b + 128,
                                                 h, h, hb, nullptr, out, 8, 260.0f);
    // layer 2 (final): writes out directly, drops virtual node
    // (canary out[9]=280 from the gemm; final attn carries NO canary and
    //  overwrites out[0..9] with real values when it runs)
    k_gemm<false><<<NN / 64, 256, 0, stream>>>(hb, WT + 65536, bl + 256, br + 256, xl, xr, out, 9, 280.0f);
    k_attn<1, true><<<NN / 4, 256, 0, stream>>>(xl, xr, row_off, adj,
                                                We + 256, att + 256, bias_p + 256,
                                                ln_g + 256, ln_b + 256,
                                                h, nullptr, nullptr, out, nullptr, 0, 0.0f);
}

// Round 14
// 537.570 us; speedup vs baseline: 3.2628x; 1.1484x over previous
//
#include <hip/hip_runtime.h>
#include <hip/hip_bf16.h>

typedef unsigned int uint;
typedef unsigned short ushort;

#define NN 65536
#define NE 1048576
#define DD 128
#define TOTE (NE + NN)   // 1114112

__device__ __forceinline__ float b2f(ushort u) {
    uint v = ((uint)u) << 16; float f; __builtin_memcpy(&f, &v, 4); return f;
}
__device__ __forceinline__ ushort f2b(float f) {
    uint x; __builtin_memcpy(&x, &f, 4);
    uint r = (x + 0x7fffu + ((x >> 16) & 1u)) >> 16;
    return (ushort)r;
}

typedef __bf16 bf16x8 __attribute__((ext_vector_type(8)));
typedef float f32x4 __attribute__((ext_vector_type(4)));
typedef float f32x2 __attribute__((ext_vector_type(2)));

// unpack 2 bf16 (packed in uint) -> packed float2, no cvt needed
__device__ __forceinline__ f32x2 bf2f2(uint u) {
    union { uint i; float f; } lo, hi;
    lo.i = u << 16; hi.i = u & 0xffff0000u;
    return (f32x2){lo.f, hi.f};
}

// Canary protocol (kept permanently; perf-free): each pre-final kernel writes a
// distinct constant into a distinct slot of out[0..9]; the FINAL k_attn
// overwrites them with real values. On a mid-pipeline failure, absmax decodes
// the last kernel that ran (100,120,...,280; bands disjoint vs max|ref|=6.5).

// ---------- init: transpose W (fp32 k-major -> bf16 n-major) + zero cnt/sumbuf ----------
__global__ void k_init(const float* __restrict__ Wl, const float* __restrict__ Wr,
                       ushort* __restrict__ WT, int* __restrict__ cnt, float* __restrict__ sumbuf,
                       float* __restrict__ cano) {
    if (cano && blockIdx.x == 0 && blockIdx.y == 0 && blockIdx.z == 0 && threadIdx.x == 0)
        cano[0] = 100.0f;
    // grid (128, 2, 3), block 128
    int k = blockIdx.x, n = threadIdx.x, lr = blockIdx.y, layer = blockIdx.z;
    const float* W = (lr ? Wr : Wl) + layer * 16384;
    WT[(layer * 2 + lr) * 16384 + n * 128 + k] = f2b(W[k * 128 + n]);
    int gid = ((blockIdx.z * 2 + blockIdx.y) * 128 + blockIdx.x) * 128 + threadIdx.x;
    if (gid < NN) cnt[gid] = 0;
    if (gid == NN) sumbuf[0] = 0.f;
}

// ---------- histogram by dst (+self loops) fused with edge_attr sum ----------
__global__ void k_histsum(const int* __restrict__ dst, const float* __restrict__ ea,
                          int* __restrict__ cnt, float* __restrict__ sum,
                          float* __restrict__ cano) {
    if (cano && blockIdx.x == 0 && threadIdx.x == 0) cano[1] = 120.0f;
    __shared__ float red[256];
    int t = threadIdx.x;
    int e = blockIdx.x * 256 + t;     // grid covers TOTE exactly
    int d = (e < NE) ? dst[e] : (e - NE);
    atomicAdd(&cnt[d], 1);
    float s = (e < NE) ? ea[e] : 0.f;
    red[t] = s; __syncthreads();
    for (int o = 128; o > 0; o >>= 1) { if (t < o) red[t] += red[t + o]; __syncthreads(); }
    if (t == 0 && red[0] != 0.f) atomicAdd(sum, red[0]);
}

__global__ void k_scanA(const int* __restrict__ cnt, int* __restrict__ row_off, int* __restrict__ bsum,
                        float* __restrict__ cano) {
    if (cano && blockIdx.x == 0 && threadIdx.x == 0) cano[2] = 140.0f;
    __shared__ int tmp[256];
    int t = threadIdx.x, i = blockIdx.x * 256 + t;
    int v = cnt[i]; tmp[t] = v; __syncthreads();
    for (int off = 1; off < 256; off <<= 1) {
        int x = (t >= off) ? tmp[t - off] : 0;
        __syncthreads();
        tmp[t] += x;
        __syncthreads();
    }
    row_off[i] = tmp[t] - v;
    if (t == 255) bsum[blockIdx.x] = tmp[255];
}

// scanC with local re-scan of bsum (eliminates scanB dispatch)
__global__ void k_scanC(int* __restrict__ row_off, const int* __restrict__ bsum, int* __restrict__ cursor,
                        float* __restrict__ cano) {
    if (cano && blockIdx.x == 0 && threadIdx.x == 0) cano[3] = 160.0f;
    __shared__ int tmp[256];
    __shared__ int excl[256];
    int t = threadIdx.x;
    int v = bsum[t]; tmp[t] = v; __syncthreads();
    for (int off = 1; off < 256; off <<= 1) {
        int x = (t >= off) ? tmp[t - off] : 0;
        __syncthreads();
        tmp[t] += x;
        __syncthreads();
    }
    excl[t] = tmp[t] - v;
    __syncthreads();
    int offb = excl[blockIdx.x];
    int i = blockIdx.x * 256 + t;
    int nv = row_off[i] + offb;
    row_off[i] = nv;
    cursor[i] = nv;
    if (i == 0) row_off[NN] = TOTE;
}

// adj.x stores src<<8 (byte offset into bf16 row array: src*128ch*2B)
__global__ void k_scatter(const int* __restrict__ src, const int* __restrict__ dst,
                          const float* __restrict__ ea, const float* __restrict__ sum,
                          int* __restrict__ cursor, int2* __restrict__ adj,
                          float* __restrict__ cano) {
    if (cano && blockIdx.x == 0 && threadIdx.x == 0) cano[4] = 180.0f;
    int e = blockIdx.x * 256 + threadIdx.x;
    int s, d; float a;
    if (e < NE) { s = src[e]; d = dst[e]; a = ea[e]; }
    else        { s = e - NE; d = s;      a = sum[0] * (1.0f / NE); }
    int pos = atomicAdd(&cursor[d], 1);
    adj[pos] = make_int2(s << 8, __float_as_int(a));
}

// ---------- dual GEMM rewrite (round 12): B-in-LDS, A direct-to-reg, LDS-transposed epilogue ----------
// R11 ARITHMETIC: non-attn time ~335us constant across R8-R11 => 3 gemms at ~95-110us
// each vs ~15us roofline (4.3GFLOP=0.5us MFMA, ~50MB=10us traffic). Old kernel's costs:
// (a) B gathered from GLOBAL inside the inner loop (128 strided 16B gathers/wave, L2
// latency exposed), (b) 64 scalar 2B stores per lane in the epilogue.
// NEW: 512-thr block = 8 waves x 16 rows = 128 rows/block, grid 512 = 2 blocks/CU.
//  1) stage BOTH B matrices to LDS once per block, chunk layout [mat][kchunk][col][8]
//     (64KB total, coalesced global reads; MFMA-fragment reads are <=2-way conflicts).
//  2) A loaded global->registers directly in fragment layout (same bytes the old LDS
//     staging produced; f32 path converts with the same f2b).
//  3) epilogue: stage C through the SAME 64KB LDS (B dead after MFMA; barrier-guarded),
//     then 16B bf16x8 coalesced stores (8/thread instead of 64 scalar 2B/lane).
// Numerics identical to the verified kernel: same conversion points, f32 bias add.
template<bool F32SRC>
__global__ __launch_bounds__(512) void k_gemm(const void* __restrict__ srcv, const ushort* __restrict__ WT,
                                              const float* __restrict__ bl, const float* __restrict__ br,
                                              ushort* __restrict__ xl, ushort* __restrict__ xr,
                                              float* __restrict__ cano, int cslot, float cval) {
    if (cano && blockIdx.x == 0 && threadIdx.x == 0) cano[cslot] = cval;
    __shared__ __align__(16) ushort S[32768];   // 64KB: B [2][16][128][8], then C [2][128][128]

    int t = threadIdx.x;
    int rowbase = blockIdx.x * 128;

    // ---- stage B (both matrices) to LDS: BS(m,c,n) = S[m*16384 + c*1024 + n*8] ----
    // global WT[m*16384 + n*128 + c*8 +0..8]; consecutive t -> c fastest -> contiguous 256B/col
    #pragma unroll
    for (int i = 0; i < 8; i++) {
        int idx = i * 512 + t;            // 0..4095 chunks of 8 bf16
        int m = idx >> 11, n = (idx >> 4) & 127, c = idx & 15;
        *(bf16x8*)&S[m * 16384 + c * 1024 + n * 8] =
            *(const bf16x8*)&WT[m * 16384 + n * 128 + c * 8];
    }

    int wave = t >> 6, lane = t & 63;
    int row16 = lane & 15, quad = lane >> 4;
    int myrow = rowbase + wave * 16 + row16;

    // per-lane bias registers (col = tc*16 + row16)
    float bbl[8], bbr[8];
    #pragma unroll
    for (int tc = 0; tc < 8; tc++) { bbl[tc] = bl[tc * 16 + row16]; bbr[tc] = br[tc * 16 + row16]; }

    f32x4 accl[8], accr[8];
    #pragma unroll
    for (int i = 0; i < 8; i++) {
        accl[i] = (f32x4){0.f, 0.f, 0.f, 0.f};
        accr[i] = (f32x4){0.f, 0.f, 0.f, 0.f};
    }

    __syncthreads();   // B staged

    #pragma unroll
    for (int ks = 0; ks < 4; ks++) {
        // A fragment: this lane's row, k-elems [ks*32+quad*8, +8) — direct from global
        bf16x8 a;
        if (F32SRC) {
            const float* src = (const float*)srcv;
            const float* pa = &src[(size_t)myrow * 128 + ks * 32 + quad * 8];
            float4 v0 = *(const float4*)pa;
            float4 v1 = *(const float4*)(pa + 4);
            ushort u[8] = {f2b(v0.x), f2b(v0.y), f2b(v0.z), f2b(v0.w),
                           f2b(v1.x), f2b(v1.y), f2b(v1.z), f2b(v1.w)};
            __builtin_memcpy(&a, u, 16);
        } else {
            a = *(const bf16x8*)&((const ushort*)srcv)[(size_t)myrow * 128 + ks * 32 + quad * 8];
        }
        int chunk = ks * 4 + quad;
        #pragma unroll
        for (int tc = 0; tc < 8; tc++) {
            int coln = tc * 16 + row16;
            bf16x8 b_l = *(const bf16x8*)&S[chunk * 1024 + coln * 8];
            bf16x8 b_r = *(const bf16x8*)&S[16384 + chunk * 1024 + coln * 8];
            accl[tc] = __builtin_amdgcn_mfma_f32_16x16x32_bf16(a, b_l, accl[tc], 0, 0, 0);
            accr[tc] = __builtin_amdgcn_mfma_f32_16x16x32_bf16(a, b_r, accr[tc], 0, 0, 0);
        }
    }

    __syncthreads();   // all B reads done; S reusable for C

    // ---- stage C to LDS: CS(m,row,col) = S[m*16384 + row*128 + col] ----
    #pragma unroll
    for (int tc = 0; tc < 8; tc++) {
        int col = tc * 16 + row16;
        #pragma unroll
        for (int r = 0; r < 4; r++) {
            int row = wave * 16 + quad * 4 + r;        // C/D: row = quad*4 + reg
            S[row * 128 + col]         = f2b(accl[tc][r] + bbl[tc]);
            S[16384 + row * 128 + col] = f2b(accr[tc][r] + bbr[tc]);
        }
    }
    __syncthreads();

    // ---- coalesced 16B stores: 2 mats x 128 rows x 128 cols = 4096 chunks, 8/thread ----
    #pragma unroll
    for (int i = 0; i < 8; i++) {
        int idx = i * 512 + t;            // consecutive t -> c8 fastest -> contiguous global
        int m = idx >> 11, row = (idx >> 4) & 127, c8 = idx & 15;
        bf16x8 v = *(const bf16x8*)&S[m * 16384 + row * 128 + c8 * 8];
        ushort* dst = m ? xr : xl;
        *(bf16x8*)&dst[(size_t)(rowbase + row) * 128 + c8 * 8] = v;
    }
}

// ---------- fused attention: R8-verified (88us) — 2-wave blocks + 4-group register prologue ----------
// R11 CLOSED THE OCCUPANCY ARC: occupancy pinned ~40% across 2-wave/4-wave/persistent
// structures; R8 (this version) is the attn optimum. Do not re-attack structure.
// Lane = (p=lane>>3: edge slot, cl=lane&7: 16-ch block). accbuf stride 20 spreads
// the 8 cl lanes across all 32 banks. Clamped slots re-read adj[s0], masked via
// valid -> logit -1e30 -> e=0. Keep min-waves<=4 ((128,8) spilled in R9: 5x slower).
template<int H, bool FINAL>
__global__ __launch_bounds__(128, 4) void k_attn(
    const ushort* __restrict__ xl, const ushort* __restrict__ xr,
    const int* __restrict__ row_off, const int2* __restrict__ adj,
    const float* __restrict__ We, const float* __restrict__ att,
    const float* __restrict__ bias, const float* __restrict__ ln_g, const float* __restrict__ ln_b,
    const float* __restrict__ hin, float* __restrict__ hout, ushort* __restrict__ hb,
    float* __restrict__ outp,
    float* __restrict__ cano, int cslot, float cval)
{
    if (cano && blockIdx.x == 0 && threadIdx.x == 0) cano[cslot] = cval;
    __shared__ float accbuf[2][8][160];   // [wave][p][cl*20 + 0..15] — bank-spread layout

    int wv = threadIdx.x >> 6, lane = threadIdx.x & 63;
    int n = blockIdx.x * 2 + wv;
    int p = lane >> 3;          // edge slot within 8-edge group
    int cl = lane & 7;          // channel block: ch [16*cl, 16*cl+16)
    int c16 = cl * 16;
    const char* xlb = (const char*)xl;

    // register caches (packed pairs)
    f32x2 we2[8], at2[8], xrl2[8];
    #pragma unroll
    for (int k = 0; k < 8; k++) {
        we2[k] = (f32x2){We[c16 + 2 * k], We[c16 + 2 * k + 1]};
        at2[k] = (f32x2){att[c16 + 2 * k], att[c16 + 2 * k + 1]};
    }
    {
        uint4 r0 = *(const uint4*)&xr[(size_t)n * 128 + c16];
        uint4 r1 = *(const uint4*)&xr[(size_t)n * 128 + c16 + 8];
        xrl2[0] = bf2f2(r0.x); xrl2[1] = bf2f2(r0.y); xrl2[2] = bf2f2(r0.z); xrl2[3] = bf2f2(r0.w);
        xrl2[4] = bf2f2(r1.x); xrl2[5] = bf2f2(r1.y); xrl2[6] = bf2f2(r1.z); xrl2[7] = bf2f2(r1.w);
    }

    int s0 = row_off[n], s1 = row_off[n + 1];
    int iters = (s1 - s0 + 7) >> 3;     // >= 1 (self-loop)

    float l_run = 0.f;
    f32x2 acc[8];
    #pragma unroll
    for (int k = 0; k < 8; k++) acc[k] = (f32x2){0.f, 0.f};

    // ---- 4-group register prologue: issue all adj loads, then all gathers ----
    int j0 = s0 + p,      j1 = s0 + 8 + p,  j2 = s0 + 16 + p, j3 = s0 + 24 + p;
    int i0 = (j0 < s1) ? j0 : s0;
    int i1 = (j1 < s1) ? j1 : s0;
    int i2 = (j2 < s1) ? j2 : s0;
    int i3 = (j3 < s1) ? j3 : s0;
    int2 a0 = adj[i0], a1 = adj[i1], a2 = adj[i2], a3 = adj[i3];
    float ea0 = (j0 < s1) ? __int_as_float(a0.y) : 0.f;
    float ea1 = (j1 < s1) ? __int_as_float(a1.y) : 0.f;
    float ea2v = (j2 < s1) ? __int_as_float(a2.y) : 0.f;
    float ea3 = (j3 < s1) ? __int_as_float(a3.y) : 0.f;
    const char* q0 = xlb + (size_t)(uint)a0.x + (cl << 5);
    const char* q1 = xlb + (size_t)(uint)a1.x + (cl << 5);
    const char* q2 = xlb + (size_t)(uint)a2.x + (cl << 5);
    const char* q3 = xlb + (size_t)(uint)a3.x + (cl << 5);
    uint4 u00 = *(const uint4*)q0, u01 = *(const uint4*)(q0 + 16);
    uint4 u10 = *(const uint4*)q1, u11 = *(const uint4*)(q1 + 16);
    uint4 u20 = *(const uint4*)q2, u21 = *(const uint4*)(q2 + 16);
    uint4 u30 = *(const uint4*)q3, u31 = *(const uint4*)(q3 + 16);

    // consume one 8-edge group held in registers (identical math to baseline)
    auto consume = [&](uint4 u0, uint4 u1, float ea_c, int itx) {
        bool valid = (s0 + itx * 8 + p) < s1;
        f32x2 xf[8];
        xf[0] = bf2f2(u0.x); xf[1] = bf2f2(u0.y); xf[2] = bf2f2(u0.z); xf[3] = bf2f2(u0.w);
        xf[4] = bf2f2(u1.x); xf[5] = bf2f2(u1.y); xf[6] = bf2f2(u1.z); xf[7] = bf2f2(u1.w);

        f32x2 ea2 = (f32x2){ea_c, ea_c};
        f32x2 s2 = (f32x2){0.f, 0.f};
        #pragma unroll
        for (int k = 0; k < 8; k++) {
            f32x2 m = xf[k] + __builtin_elementwise_fma(ea2, we2[k], xrl2[k]);
            m = __builtin_elementwise_max(m, 0.2f * m);     // leaky_relu(0.2)
            s2 = __builtin_elementwise_fma(m, at2[k], s2);
        }
        float s = s2.x + s2.y;
        // head reduction across cl lanes of same edge
        s += __shfl_xor(s, 1);
        if (H == 1) { s += __shfl_xor(s, 2); s += __shfl_xor(s, 4); }
        if (!valid) s = -1e30f;

        float e = __expf(s);                 // 0 for invalid; no overflow (|s| small)
        l_run += e;
        f32x2 e2 = (f32x2){e, e};
        #pragma unroll
        for (int k = 0; k < 8; k++) acc[k] = __builtin_elementwise_fma(e2, xf[k], acc[k]);
    };

    consume(u00, u01, ea0, 0);
    if (iters > 1) consume(u10, u11, ea1, 1);
    if (iters > 2) consume(u20, u21, ea2v, 2);
    if (iters > 3) consume(u30, u31, ea3, 3);
    // rare tail: degree > 32 (~0.03% of nodes), simple serial loads
    for (int it = 4; it < iters; ++it) {
        int jn = s0 + it * 8 + p;
        int jb = (jn < s1) ? jn : s0;
        int2 pk = adj[jb];
        float ean = (jn < s1) ? __int_as_float(pk.y) : 0.f;
        const char* rp = xlb + (size_t)(uint)pk.x + (cl << 5);
        uint4 nu0 = *(const uint4*)rp;
        uint4 nu1 = *(const uint4*)(rp + 16);
        consume(nu0, nu1, ean, it);
    }

    // per-head denominator over the 8 edge slots (p)
    l_run += __shfl_xor(l_run, 8);
    l_run += __shfl_xor(l_run, 16);
    l_run += __shfl_xor(l_run, 32);
    float inv = 1.0f / (l_run + 1e-16f);     // matches this lane's channels' head

    // write inv-premultiplied partials to LDS tile (bank-spread: base cl*20)
    float* row = &accbuf[wv][p][cl * 20];
    #pragma unroll
    for (int i = 0; i < 4; i++)
        *(float4*)&row[4 * i] = make_float4(acc[2 * i].x * inv, acc[2 * i].y * inv,
                                            acc[2 * i + 1].x * inv, acc[2 * i + 1].y * inv);
    __syncthreads();

    // each lane sums its 2 channels across the 8 p-slots
    int c0 = 2 * lane;
    int rb = (c0 >> 4) * 20 + (c0 & 15);
    float o0 = 0.f, o1 = 0.f;
    #pragma unroll
    for (int q = 0; q < 8; q++) {
        float2 v = *(float2*)&accbuf[wv][q][rb];
        o0 += v.x; o1 += v.y;
    }
    o0 += bias[c0];
    o1 += bias[c0 + 1];

    // LayerNorm over 128 channels (2 per lane)
    float sred = o0 + o1;
    #pragma unroll
    for (int off = 1; off < 64; off <<= 1) sred += __shfl_xor(sred, off);
    float mu = sred * (1.f / 128.f);
    float d0 = o0 - mu, d1 = o1 - mu;
    float v = d0 * d0 + d1 * d1;
    #pragma unroll
    for (int off = 1; off < 64; off <<= 1) v += __shfl_xor(v, off);
    float rstd = rsqrtf(v * (1.f / 128.f) + 1e-5f);
    o0 = d0 * rstd * ln_g[c0] + ln_b[c0];
    o1 = d1 * rstd * ln_g[c0 + 1] + ln_b[c0 + 1];

    float2 hv = *(const float2*)&hin[(size_t)n * 128 + c0];
    if (FINAL) {
        float r0 = hv.x + o0, r1 = hv.y + o1;
        int g = n >> 9, rr = n & 511;
        if (rr < 511)
            *(float2*)&outp[((size_t)(g * 511 + rr)) * 128 + c0] = make_float2(r0, r1);
    } else {
        o0 = 0.5f * o0 * (1.f + erff(o0 * 0.70710678118f));   // exact GELU
        o1 = 0.5f * o1 * (1.f + erff(o1 * 0.70710678118f));
        hv.x += o0; hv.y += o1;
        *(float2*)&hout[(size_t)n * 128 + c0] = hv;
        uint pk = (uint)f2b(hv.x) | ((uint)f2b(hv.y) << 16);
        *(uint*)&hb[(size_t)n * 128 + c0] = pk;
    }
}

extern "C" void kernel_launch(void* const* d_in, const int* in_sizes, int n_in,
                              void* d_out, int out_size, void* d_ws, size_t ws_size,
                              hipStream_t stream) {
    const float* x        = (const float*)d_in[0];
    const int*   edge_src = (const int*)d_in[1];
    const int*   edge_dst = (const int*)d_in[2];
    const float* edge_attr= (const float*)d_in[3];
    const float* Wl       = (const float*)d_in[4];
    const float* bl       = (const float*)d_in[5];
    const float* Wr       = (const float*)d_in[6];
    const float* br       = (const float*)d_in[7];
    const float* We       = (const float*)d_in[8];
    const float* att      = (const float*)d_in[9];
    const float* bias_p   = (const float*)d_in[10];
    const float* ln_g     = (const float*)d_in[11];
    const float* ln_b     = (const float*)d_in[12];
    float* out = (float*)d_out;

    char* ws = (char*)d_ws;
    float*  h       = (float*)(ws + 0);                 // 33,554,432
    ushort* hb      = (ushort*)(ws + 33554432);         // 16,777,216
    ushort* xl      = (ushort*)(ws + 50331648);         // 16,777,216
    ushort* xr      = (ushort*)(ws + 67108864);         // 16,777,216
    int2*   adj     = (int2*)(ws + 83886080);           //  8,912,896
    int*    row_off = (int*)(ws + 92798976);            //    262,400 (incl pad)
    int*    cnt     = (int*)(ws + 93061376);            //    262,144 (also cursor)
    int*    bsum    = (int*)(ws + 93323520);            //      1,024
    float*  sumbuf  = (float*)(ws + 93324544);          //        256
    ushort* WT      = (ushort*)(ws + 93324800);         //    196,608 (3 layers x 2)

    // 1: transpose weights + zero cnt/sumbuf  (canary out[0]=100)
    k_init<<<dim3(128, 2, 3), 128, 0, stream>>>(Wl, Wr, WT, cnt, sumbuf, out);
    // 2: histogram + edge_attr sum            (canary out[1]=120)
    k_histsum<<<TOTE / 256, 256, 0, stream>>>(edge_dst, edge_attr, cnt, sumbuf, out);
    // 3-4: scan                               (canaries out[2]=140, out[3]=160)
    k_scanA<<<NN / 256, 256, 0, stream>>>(cnt, row_off, bsum, out);
    k_scanC<<<NN / 256, 256, 0, stream>>>(row_off, bsum, cnt, out);
    // 5: scatter (adj.x = src byte offset)    (canary out[4]=180)
    k_scatter<<<TOTE / 256, 256, 0, stream>>>(edge_src, edge_dst, edge_attr, sumbuf, cnt, adj, out);

    // layer 0: GEMM from fp32 x; residual from x   (canaries out[5]=200, out[6]=220)
    k_gemm<true><<<NN / 128, 512, 0, stream>>>(x, WT, bl, br, xl, xr, out, 5, 200.0f);
    k_attn<4, false><<<NN / 2, 128, 0, stream>>>(xl, xr, row_off, adj,
                                                 We, att, bias_p, ln_g, ln_b,
                                                 x, h, hb, nullptr, out, 6, 220.0f);
    // layer 1                                       (canaries out[7]=240, out[8]=260)
    k_gemm<false><<<NN / 128, 512, 0, stream>>>(hb, WT + 32768, bl + 128, br + 128, xl, xr, out, 7, 240.0f);
    k_attn<4, false><<<NN / 2, 128, 0, stream>>>(xl, xr, row_off, adj,
                                                 We + 128, att + 128, bias_p + 128,
                                                 ln_g + 128, ln_b + 128,
                                                 h, h, hb, nullptr, out, 8, 260.0f);
    // layer 2 (final): writes out directly, drops virtual node
    // (canary out[9]=280 from the gemm; final attn carries NO canary and
    //  overwrites out[0..9] with real values when it runs)
    k_gemm<false><<<NN / 128, 512, 0, stream>>>(hb, WT + 65536, bl + 256, br + 256, xl, xr, out, 9, 280.0f);
    k_attn<1, true><<<NN / 2, 128, 0, stream>>>(xl, xr, row_off, adj,
                                                We + 256, att + 256, bias_p + 256,
                                                ln_g + 256, ln_b + 256,
                                                h, nullptr, nullptr, out, nullptr, 0, 0.0f);
}

// Round 15
// 520.940 us; speedup vs baseline: 3.3670x; 1.0319x over previous
//
#include <hip/hip_runtime.h>
#include <hip/hip_bf16.h>

typedef unsigned int uint;
typedef unsigned short ushort;

#define NN 65536
#define NE 1048576
#define DD 128
#define TOTE (NE + NN)   // 1114112

__device__ __forceinline__ float b2f(ushort u) {
    uint v = ((uint)u) << 16; float f; __builtin_memcpy(&f, &v, 4); return f;
}
__device__ __forceinline__ ushort f2b(float f) {
    uint x; __builtin_memcpy(&x, &f, 4);
    uint r = (x + 0x7fffu + ((x >> 16) & 1u)) >> 16;
    return (ushort)r;
}

typedef __bf16 bf16x8 __attribute__((ext_vector_type(8)));
typedef float f32x4 __attribute__((ext_vector_type(4)));
typedef float f32x2 __attribute__((ext_vector_type(2)));

// unpack 2 bf16 (packed in uint) -> packed float2, no cvt needed
__device__ __forceinline__ f32x2 bf2f2(uint u) {
    union { uint i; float f; } lo, hi;
    lo.i = u << 16; hi.i = u & 0xffff0000u;
    return (f32x2){lo.f, hi.f};
}

// Canary protocol (kept permanently; perf-free): each pre-final kernel writes a
// distinct constant into a distinct slot of out[0..9]; the FINAL k_attn
// overwrites them with real values. On a mid-pipeline failure, absmax decodes
// the last kernel that ran (100,120,...,280; bands disjoint vs max|ref|=6.5).

// ---------- init: transpose W (fp32 k-major -> bf16 n-major) + zero cnt/sumbuf ----------
__global__ void k_init(const float* __restrict__ Wl, const float* __restrict__ Wr,
                       ushort* __restrict__ WT, int* __restrict__ cnt, float* __restrict__ sumbuf,
                       float* __restrict__ cano) {
    if (cano && blockIdx.x == 0 && blockIdx.y == 0 && blockIdx.z == 0 && threadIdx.x == 0)
        cano[0] = 100.0f;
    // grid (128, 2, 3), block 128
    int k = blockIdx.x, n = threadIdx.x, lr = blockIdx.y, layer = blockIdx.z;
    const float* W = (lr ? Wr : Wl) + layer * 16384;
    WT[(layer * 2 + lr) * 16384 + n * 128 + k] = f2b(W[k * 128 + n]);
    int gid = ((blockIdx.z * 2 + blockIdx.y) * 128 + blockIdx.x) * 128 + threadIdx.x;
    if (gid < NN) cnt[gid] = 0;
    if (gid == NN) sumbuf[0] = 0.f;
}

// ---------- histogram by dst (+self loops) fused with edge_attr sum — 4 edges/thread ----------
// TOTE = 1088*1024 exactly; NE divisible by 4 -> each 4-pack is entirely edges or
// entirely self-loops (no straddle). Vectorized int4/float4 loads, 1/4 the waves.
__global__ void k_histsum(const int* __restrict__ dst, const float* __restrict__ ea,
                          int* __restrict__ cnt, float* __restrict__ sum,
                          float* __restrict__ cano) {
    if (cano && blockIdx.x == 0 && threadIdx.x == 0) cano[1] = 120.0f;
    __shared__ float red[256];
    int t = threadIdx.x;
    int e0 = (blockIdx.x * 256 + t) * 4;
    float s = 0.f;
    if (e0 < NE) {
        int4  d4 = *(const int4*)&dst[e0];
        float4 a4 = *(const float4*)&ea[e0];
        atomicAdd(&cnt[d4.x], 1); atomicAdd(&cnt[d4.y], 1);
        atomicAdd(&cnt[d4.z], 1); atomicAdd(&cnt[d4.w], 1);
        s = (a4.x + a4.y) + (a4.z + a4.w);
    } else {
        int b = e0 - NE;
        atomicAdd(&cnt[b], 1);     atomicAdd(&cnt[b + 1], 1);
        atomicAdd(&cnt[b + 2], 1); atomicAdd(&cnt[b + 3], 1);
    }
    red[t] = s; __syncthreads();
    for (int o = 128; o > 0; o >>= 1) { if (t < o) red[t] += red[t + o]; __syncthreads(); }
    if (t == 0 && red[0] != 0.f) atomicAdd(sum, red[0]);
}

__global__ void k_scanA(const int* __restrict__ cnt, int* __restrict__ row_off, int* __restrict__ bsum,
                        float* __restrict__ cano) {
    if (cano && blockIdx.x == 0 && threadIdx.x == 0) cano[2] = 140.0f;
    __shared__ int tmp[256];
    int t = threadIdx.x, i = blockIdx.x * 256 + t;
    int v = cnt[i]; tmp[t] = v; __syncthreads();
    for (int off = 1; off < 256; off <<= 1) {
        int x = (t >= off) ? tmp[t - off] : 0;
        __syncthreads();
        tmp[t] += x;
        __syncthreads();
    }
    row_off[i] = tmp[t] - v;
    if (t == 255) bsum[blockIdx.x] = tmp[255];
}

// scanC with local re-scan of bsum (eliminates scanB dispatch)
__global__ void k_scanC(int* __restrict__ row_off, const int* __restrict__ bsum, int* __restrict__ cursor,
                        float* __restrict__ cano) {
    if (cano && blockIdx.x == 0 && threadIdx.x == 0) cano[3] = 160.0f;
    __shared__ int tmp[256];
    __shared__ int excl[256];
    int t = threadIdx.x;
    int v = bsum[t]; tmp[t] = v; __syncthreads();
    for (int off = 1; off < 256; off <<= 1) {
        int x = (t >= off) ? tmp[t - off] : 0;
        __syncthreads();
        tmp[t] += x;
        __syncthreads();
    }
    excl[t] = tmp[t] - v;
    __syncthreads();
    int offb = excl[blockIdx.x];
    int i = blockIdx.x * 256 + t;
    int nv = row_off[i] + offb;
    row_off[i] = nv;
    cursor[i] = nv;
    if (i == 0) row_off[NN] = TOTE;
}

// adj.x stores src<<8 (byte offset into bf16 row array: src*128ch*2B) — 4 edges/thread
__global__ void k_scatter(const int* __restrict__ src, const int* __restrict__ dst,
                          const float* __restrict__ ea, const float* __restrict__ sum,
                          int* __restrict__ cursor, int2* __restrict__ adj,
                          float* __restrict__ cano) {
    if (cano && blockIdx.x == 0 && threadIdx.x == 0) cano[4] = 180.0f;
    int e0 = (blockIdx.x * 256 + threadIdx.x) * 4;
    if (e0 < NE) {
        int4  s4 = *(const int4*)&src[e0];
        int4  d4 = *(const int4*)&dst[e0];
        float4 a4 = *(const float4*)&ea[e0];
        int p0 = atomicAdd(&cursor[d4.x], 1); adj[p0] = make_int2(s4.x << 8, __float_as_int(a4.x));
        int p1 = atomicAdd(&cursor[d4.y], 1); adj[p1] = make_int2(s4.y << 8, __float_as_int(a4.y));
        int p2 = atomicAdd(&cursor[d4.z], 1); adj[p2] = make_int2(s4.z << 8, __float_as_int(a4.z));
        int p3 = atomicAdd(&cursor[d4.w], 1); adj[p3] = make_int2(s4.w << 8, __float_as_int(a4.w));
    } else {
        int b = e0 - NE;
        float a = sum[0] * (1.0f / NE);
        #pragma unroll
        for (int k = 0; k < 4; k++) {
            int p = atomicAdd(&cursor[b + k], 1);
            adj[p] = make_int2((b + k) << 8, __float_as_int(a));
        }
    }
}

// ---------- dual GEMM (R14-verified, −78us) + R15 delta: A-loads hoisted before barrier ----------
// 512-thr block = 8 waves x 16 rows = 128 rows/block, grid 512 = 2 blocks/CU.
// B staged once per block to LDS [mat][kchunk][col][8] (64KB); A global->reg in
// fragment layout; C transposed through the same LDS into coalesced 16B stores.
// R15: all 4 A-fragment loads ISSUED BEFORE the staging barrier (compiler cannot
// hoist loads across __syncthreads) -> A latency fully overlaps B staging.
template<bool F32SRC>
__global__ __launch_bounds__(512) void k_gemm(const void* __restrict__ srcv, const ushort* __restrict__ WT,
                                              const float* __restrict__ bl, const float* __restrict__ br,
                                              ushort* __restrict__ xl, ushort* __restrict__ xr,
                                              float* __restrict__ cano, int cslot, float cval) {
    if (cano && blockIdx.x == 0 && threadIdx.x == 0) cano[cslot] = cval;
    __shared__ __align__(16) ushort S[32768];   // 64KB: B [2][16][128][8], then C [2][128][128]

    int t = threadIdx.x;
    int rowbase = blockIdx.x * 128;

    // ---- stage B (both matrices) to LDS: BS(m,c,n) = S[m*16384 + c*1024 + n*8] ----
    #pragma unroll
    for (int i = 0; i < 8; i++) {
        int idx = i * 512 + t;            // 0..4095 chunks of 8 bf16
        int m = idx >> 11, n = (idx >> 4) & 127, c = idx & 15;
        *(bf16x8*)&S[m * 16384 + c * 1024 + n * 8] =
            *(const bf16x8*)&WT[m * 16384 + n * 128 + c * 8];
    }

    int wave = t >> 6, lane = t & 63;
    int row16 = lane & 15, quad = lane >> 4;
    int myrow = rowbase + wave * 16 + row16;

    // ---- A fragments: issue ALL loads now (overlap B staging + barrier) ----
    bf16x8 areg[4];
    if (F32SRC) {
        const float* src = (const float*)srcv;
        float4 av[8];
        #pragma unroll
        for (int ks = 0; ks < 4; ks++) {
            const float* pa = &src[(size_t)myrow * 128 + ks * 32 + quad * 8];
            av[2 * ks]     = *(const float4*)pa;
            av[2 * ks + 1] = *(const float4*)(pa + 4);
        }
        #pragma unroll
        for (int ks = 0; ks < 4; ks++) {
            ushort u[8] = {f2b(av[2 * ks].x), f2b(av[2 * ks].y), f2b(av[2 * ks].z), f2b(av[2 * ks].w),
                           f2b(av[2 * ks + 1].x), f2b(av[2 * ks + 1].y), f2b(av[2 * ks + 1].z), f2b(av[2 * ks + 1].w)};
            __builtin_memcpy(&areg[ks], u, 16);
        }
    } else {
        const ushort* src = (const ushort*)srcv;
        #pragma unroll
        for (int ks = 0; ks < 4; ks++)
            areg[ks] = *(const bf16x8*)&src[(size_t)myrow * 128 + ks * 32 + quad * 8];
    }

    // per-lane bias registers (col = tc*16 + row16)
    float bbl[8], bbr[8];
    #pragma unroll
    for (int tc = 0; tc < 8; tc++) { bbl[tc] = bl[tc * 16 + row16]; bbr[tc] = br[tc * 16 + row16]; }

    f32x4 accl[8], accr[8];
    #pragma unroll
    for (int i = 0; i < 8; i++) {
        accl[i] = (f32x4){0.f, 0.f, 0.f, 0.f};
        accr[i] = (f32x4){0.f, 0.f, 0.f, 0.f};
    }

    __syncthreads();   // B staged (A already in registers)

    #pragma unroll
    for (int ks = 0; ks < 4; ks++) {
        int chunk = ks * 4 + quad;
        #pragma unroll
        for (int tc = 0; tc < 8; tc++) {
            int coln = tc * 16 + row16;
            bf16x8 b_l = *(const bf16x8*)&S[chunk * 1024 + coln * 8];
            bf16x8 b_r = *(const bf16x8*)&S[16384 + chunk * 1024 + coln * 8];
            accl[tc] = __builtin_amdgcn_mfma_f32_16x16x32_bf16(areg[ks], b_l, accl[tc], 0, 0, 0);
            accr[tc] = __builtin_amdgcn_mfma_f32_16x16x32_bf16(areg[ks], b_r, accr[tc], 0, 0, 0);
        }
    }

    __syncthreads();   // all B reads done; S reusable for C

    // ---- stage C to LDS: CS(m,row,col) = S[m*16384 + row*128 + col] ----
    #pragma unroll
    for (int tc = 0; tc < 8; tc++) {
        int col = tc * 16 + row16;
        #pragma unroll
        for (int r = 0; r < 4; r++) {
            int row = wave * 16 + quad * 4 + r;        // C/D: row = quad*4 + reg
            S[row * 128 + col]         = f2b(accl[tc][r] + bbl[tc]);
            S[16384 + row * 128 + col] = f2b(accr[tc][r] + bbr[tc]);
        }
    }
    __syncthreads();

    // ---- coalesced 16B stores: 2 mats x 128 rows x 128 cols = 4096 chunks, 8/thread ----
    #pragma unroll
    for (int i = 0; i < 8; i++) {
        int idx = i * 512 + t;            // consecutive t -> c8 fastest -> contiguous global
        int m = idx >> 11, row = (idx >> 4) & 127, c8 = idx & 15;
        bf16x8 v = *(const bf16x8*)&S[m * 16384 + row * 128 + c8 * 8];
        ushort* dst = m ? xr : xl;
        *(bf16x8*)&dst[(size_t)(rowbase + row) * 128 + c8 * 8] = v;
    }
}

// ---------- fused attention: R8-verified structure + R15 tanh-GELU ----------
// Occupancy arc closed (R9-R11): ~40% across all structures; R8 2-wave blocks optimal.
// R15 delta: exact erff GELU -> tanh-form via sigmoid identity
//   0.5*(1+tanh(u)) = 1/(1+e^{-2u}), u = 0.79788456*(x + 0.044715 x^3)
// (max abs err ~3e-3 vs threshold 0.19375; saves ~25 VALU ops/lane).
// Keep min-waves<=4 ((128,8) spilled in R9: 5x slower).
template<int H, bool FINAL>
__global__ __launch_bounds__(128, 4) void k_attn(
    const ushort* __restrict__ xl, const ushort* __restrict__ xr,
    const int* __restrict__ row_off, const int2* __restrict__ adj,
    const float* __restrict__ We, const float* __restrict__ att,
    const float* __restrict__ bias, const float* __restrict__ ln_g, const float* __restrict__ ln_b,
    const float* __restrict__ hin, float* __restrict__ hout, ushort* __restrict__ hb,
    float* __restrict__ outp,
    float* __restrict__ cano, int cslot, float cval)
{
    if (cano && blockIdx.x == 0 && threadIdx.x == 0) cano[cslot] = cval;
    __shared__ float accbuf[2][8][160];   // [wave][p][cl*20 + 0..15] — bank-spread layout

    int wv = threadIdx.x >> 6, lane = threadIdx.x & 63;
    int n = blockIdx.x * 2 + wv;
    int p = lane >> 3;          // edge slot within 8-edge group
    int cl = lane & 7;          // channel block: ch [16*cl, 16*cl+16)
    int c16 = cl * 16;
    const char* xlb = (const char*)xl;

    // register caches (packed pairs)
    f32x2 we2[8], at2[8], xrl2[8];
    #pragma unroll
    for (int k = 0; k < 8; k++) {
        we2[k] = (f32x2){We[c16 + 2 * k], We[c16 + 2 * k + 1]};
        at2[k] = (f32x2){att[c16 + 2 * k], att[c16 + 2 * k + 1]};
    }
    {
        uint4 r0 = *(const uint4*)&xr[(size_t)n * 128 + c16];
        uint4 r1 = *(const uint4*)&xr[(size_t)n * 128 + c16 + 8];
        xrl2[0] = bf2f2(r0.x); xrl2[1] = bf2f2(r0.y); xrl2[2] = bf2f2(r0.z); xrl2[3] = bf2f2(r0.w);
        xrl2[4] = bf2f2(r1.x); xrl2[5] = bf2f2(r1.y); xrl2[6] = bf2f2(r1.z); xrl2[7] = bf2f2(r1.w);
    }

    int s0 = row_off[n], s1 = row_off[n + 1];
    int iters = (s1 - s0 + 7) >> 3;     // >= 1 (self-loop)

    float l_run = 0.f;
    f32x2 acc[8];
    #pragma unroll
    for (int k = 0; k < 8; k++) acc[k] = (f32x2){0.f, 0.f};

    // ---- 4-group register prologue: issue all adj loads, then all gathers ----
    int j0 = s0 + p,      j1 = s0 + 8 + p,  j2 = s0 + 16 + p, j3 = s0 + 24 + p;
    int i0 = (j0 < s1) ? j0 : s0;
    int i1 = (j1 < s1) ? j1 : s0;
    int i2 = (j2 < s1) ? j2 : s0;
    int i3 = (j3 < s1) ? j3 : s0;
    int2 a0 = adj[i0], a1 = adj[i1], a2 = adj[i2], a3 = adj[i3];
    float ea0 = (j0 < s1) ? __int_as_float(a0.y) : 0.f;
    float ea1 = (j1 < s1) ? __int_as_float(a1.y) : 0.f;
    float ea2v = (j2 < s1) ? __int_as_float(a2.y) : 0.f;
    float ea3 = (j3 < s1) ? __int_as_float(a3.y) : 0.f;
    const char* q0 = xlb + (size_t)(uint)a0.x + (cl << 5);
    const char* q1 = xlb + (size_t)(uint)a1.x + (cl << 5);
    const char* q2 = xlb + (size_t)(uint)a2.x + (cl << 5);
    const char* q3 = xlb + (size_t)(uint)a3.x + (cl << 5);
    uint4 u00 = *(const uint4*)q0, u01 = *(const uint4*)(q0 + 16);
    uint4 u10 = *(const uint4*)q1, u11 = *(const uint4*)(q1 + 16);
    uint4 u20 = *(const uint4*)q2, u21 = *(const uint4*)(q2 + 16);
    uint4 u30 = *(const uint4*)q3, u31 = *(const uint4*)(q3 + 16);

    // consume one 8-edge group held in registers (identical math to baseline)
    auto consume = [&](uint4 u0, uint4 u1, float ea_c, int itx) {
        bool valid = (s0 + itx * 8 + p) < s1;
        f32x2 xf[8];
        xf[0] = bf2f2(u0.x); xf[1] = bf2f2(u0.y); xf[2] = bf2f2(u0.z); xf[3] = bf2f2(u0.w);
        xf[4] = bf2f2(u1.x); xf[5] = bf2f2(u1.y); xf[6] = bf2f2(u1.z); xf[7] = bf2f2(u1.w);

        f32x2 ea2 = (f32x2){ea_c, ea_c};
        f32x2 s2 = (f32x2){0.f, 0.f};
        #pragma unroll
        for (int k = 0; k < 8; k++) {
            f32x2 m = xf[k] + __builtin_elementwise_fma(ea2, we2[k], xrl2[k]);
            m = __builtin_elementwise_max(m, 0.2f * m);     // leaky_relu(0.2)
            s2 = __builtin_elementwise_fma(m, at2[k], s2);
        }
        float s = s2.x + s2.y;
        // head reduction across cl lanes of same edge
        s += __shfl_xor(s, 1);
        if (H == 1) { s += __shfl_xor(s, 2); s += __shfl_xor(s, 4); }
        if (!valid) s = -1e30f;

        float e = __expf(s);                 // 0 for invalid; no overflow (|s| small)
        l_run += e;
        f32x2 e2 = (f32x2){e, e};
        #pragma unroll
        for (int k = 0; k < 8; k++) acc[k] = __builtin_elementwise_fma(e2, xf[k], acc[k]);
    };

    consume(u00, u01, ea0, 0);
    if (iters > 1) consume(u10, u11, ea1, 1);
    if (iters > 2) consume(u20, u21, ea2v, 2);
    if (iters > 3) consume(u30, u31, ea3, 3);
    // rare tail: degree > 32 (~0.03% of nodes), simple serial loads
    for (int it = 4; it < iters; ++it) {
        int jn = s0 + it * 8 + p;
        int jb = (jn < s1) ? jn : s0;
        int2 pk = adj[jb];
        float ean = (jn < s1) ? __int_as_float(pk.y) : 0.f;
        const char* rp = xlb + (size_t)(uint)pk.x + (cl << 5);
        uint4 nu0 = *(const uint4*)rp;
        uint4 nu1 = *(const uint4*)(rp + 16);
        consume(nu0, nu1, ean, it);
    }

    // per-head denominator over the 8 edge slots (p)
    l_run += __shfl_xor(l_run, 8);
    l_run += __shfl_xor(l_run, 16);
    l_run += __shfl_xor(l_run, 32);
    float inv = 1.0f / (l_run + 1e-16f);     // matches this lane's channels' head

    // write inv-premultiplied partials to LDS tile (bank-spread: base cl*20)
    float* row = &accbuf[wv][p][cl * 20];
    #pragma unroll
    for (int i = 0; i < 4; i++)
        *(float4*)&row[4 * i] = make_float4(acc[2 * i].x * inv, acc[2 * i].y * inv,
                                            acc[2 * i + 1].x * inv, acc[2 * i + 1].y * inv);
    __syncthreads();

    // each lane sums its 2 channels across the 8 p-slots
    int c0 = 2 * lane;
    int rb = (c0 >> 4) * 20 + (c0 & 15);
    float o0 = 0.f, o1 = 0.f;
    #pragma unroll
    for (int q = 0; q < 8; q++) {
        float2 v = *(float2*)&accbuf[wv][q][rb];
        o0 += v.x; o1 += v.y;
    }
    o0 += bias[c0];
    o1 += bias[c0 + 1];

    // LayerNorm over 128 channels (2 per lane)
    float sred = o0 + o1;
    #pragma unroll
    for (int off = 1; off < 64; off <<= 1) sred += __shfl_xor(sred, off);
    float mu = sred * (1.f / 128.f);
    float d0 = o0 - mu, d1 = o1 - mu;
    float v = d0 * d0 + d1 * d1;
    #pragma unroll
    for (int off = 1; off < 64; off <<= 1) v += __shfl_xor(v, off);
    float rstd = rsqrtf(v * (1.f / 128.f) + 1e-5f);
    o0 = d0 * rstd * ln_g[c0] + ln_b[c0];
    o1 = d1 * rstd * ln_g[c0 + 1] + ln_b[c0 + 1];

    float2 hv = *(const float2*)&hin[(size_t)n * 128 + c0];
    if (FINAL) {
        float r0 = hv.x + o0, r1 = hv.y + o1;
        int g = n >> 9, rr = n & 511;
        if (rr < 511)
            *(float2*)&outp[((size_t)(g * 511 + rr)) * 128 + c0] = make_float2(r0, r1);
    } else {
        // tanh-approx GELU: x * sigmoid(2u), u = 0.79788456*(x + 0.044715 x^3)
        float t0 = o0 * (0.79788456f + 0.03567741f * o0 * o0);
        o0 = __fdividef(o0, 1.f + __expf(-2.f * t0));
        float t1 = o1 * (0.79788456f + 0.03567741f * o1 * o1);
        o1 = __fdividef(o1, 1.f + __expf(-2.f * t1));
        hv.x += o0; hv.y += o1;
        *(float2*)&hout[(size_t)n * 128 + c0] = hv;
        uint pk = (uint)f2b(hv.x) | ((uint)f2b(hv.y) << 16);
        *(uint*)&hb[(size_t)n * 128 + c0] = pk;
    }
}

extern "C" void kernel_launch(void* const* d_in, const int* in_sizes, int n_in,
                              void* d_out, int out_size, void* d_ws, size_t ws_size,
                              hipStream_t stream) {
    const float* x        = (const float*)d_in[0];
    const int*   edge_src = (const int*)d_in[1];
    const int*   edge_dst = (const int*)d_in[2];
    const float* edge_attr= (const float*)d_in[3];
    const float* Wl       = (const float*)d_in[4];
    const float* bl       = (const float*)d_in[5];
    const float* Wr       = (const float*)d_in[6];
    const float* br       = (const float*)d_in[7];
    const float* We       = (const float*)d_in[8];
    const float* att      = (const float*)d_in[9];
    const float* bias_p   = (const float*)d_in[10];
    const float* ln_g     = (const float*)d_in[11];
    const float* ln_b     = (const float*)d_in[12];
    float* out = (float*)d_out;

    char* ws = (char*)d_ws;
    float*  h       = (float*)(ws + 0);                 // 33,554,432
    ushort* hb      = (ushort*)(ws + 33554432);         // 16,777,216
    ushort* xl      = (ushort*)(ws + 50331648);         // 16,777,216
    ushort* xr      = (ushort*)(ws + 67108864);         // 16,777,216
    int2*   adj     = (int2*)(ws + 83886080);           //  8,912,896
    int*    row_off = (int*)(ws + 92798976);            //    262,400 (incl pad)
    int*    cnt     = (int*)(ws + 93061376);            //    262,144 (also cursor)
    int*    bsum    = (int*)(ws + 93323520);            //      1,024
    float*  sumbuf  = (float*)(ws + 93324544);          //        256
    ushort* WT      = (ushort*)(ws + 93324800);         //    196,608 (3 layers x 2)

    // 1: transpose weights + zero cnt/sumbuf  (canary out[0]=100)
    k_init<<<dim3(128, 2, 3), 128, 0, stream>>>(Wl, Wr, WT, cnt, sumbuf, out);
    // 2: histogram + edge_attr sum, 4 edges/thread  (canary out[1]=120)
    k_histsum<<<TOTE / 1024, 256, 0, stream>>>(edge_dst, edge_attr, cnt, sumbuf, out);
    // 3-4: scan                               (canaries out[2]=140, out[3]=160)
    k_scanA<<<NN / 256, 256, 0, stream>>>(cnt, row_off, bsum, out);
    k_scanC<<<NN / 256, 256, 0, stream>>>(row_off, bsum, cnt, out);
    // 5: scatter, 4 edges/thread (adj.x = src byte offset)  (canary out[4]=180)
    k_scatter<<<TOTE / 1024, 256, 0, stream>>>(edge_src, edge_dst, edge_attr, sumbuf, cnt, adj, out);

    // layer 0: GEMM from fp32 x; residual from x   (canaries out[5]=200, out[6]=220)
    k_gemm<true><<<NN / 128, 512, 0, stream>>>(x, WT, bl, br, xl, xr, out, 5, 200.0f);
    k_attn<4, false><<<NN / 2, 128, 0, stream>>>(xl, xr, row_off, adj,
                                                 We, att, bias_p, ln_g, ln_b,
                                                 x, h, hb, nullptr, out, 6, 220.0f);
    // layer 1                                       (canaries out[7]=240, out[8]=260)
    k_gemm<false><<<NN / 128, 512, 0, stream>>>(hb, WT + 32768, bl + 128, br + 128, xl, xr, out, 7, 240.0f);
    k_attn<4, false><<<NN / 2, 128, 0, stream>>>(xl, xr, row_off, adj,
                                                 We + 128, att + 128, bias_p + 128,
                                                 ln_g + 128, ln_b + 128,
                                                 h, h, hb, nullptr, out, 8, 260.0f);
    // layer 2 (final): writes out directly, drops virtual node
    // (canary out[9]=280 from the gemm; final attn carries NO canary and
    //  overwrites out[0..9] with real values when it runs)
    k_gemm<false><<<NN / 128, 512, 0, stream>>>(hb, WT + 65536, bl + 256, br + 256, xl, xr, out, 9, 280.0f);
    k_attn<1, true><<<NN / 2, 128, 0, stream>>>(xl, xr, row_off, adj,
                                                We + 256, att + 256, bias_p + 256,
                                                ln_g + 256, ln_b + 256,
                                                h, nullptr, nullptr, out, nullptr, 0, 0.0f);
}